// Round 14
// baseline (222.629 us; speedup 1.0000x reference)
//
#include <hip/hip_runtime.h>
#include <hip/hip_bf16.h>
#include <math.h>

#define CH 64
#define NPOS 9216   // 96*96
#define NTOT 18432  // 2*9216
#define NSPLIT 8
#define TILES_PER_SPLIT 18   // 144/8
#define LOG2E 1.4426950408889634f

typedef short bf16x8 __attribute__((ext_vector_type(8)));
typedef short bf16x4 __attribute__((ext_vector_type(4)));
typedef float f32x4 __attribute__((ext_vector_type(4)));
typedef int   i32x4 __attribute__((ext_vector_type(4)));
typedef unsigned int u32;

__device__ __forceinline__ float bf2f(short s) {
  unsigned int u = ((unsigned int)(unsigned short)s) << 16;
  return __builtin_bit_cast(float, u);
}
__device__ __forceinline__ short f2bf(float f) {
  unsigned int u = __builtin_bit_cast(unsigned int, f);
  unsigned int r = (u + 0x7fffu + ((u >> 16) & 1u)) >> 16;  // RNE
  return (short)r;
}
__device__ __forceinline__ float gelu_exact(float x) {
  return 0.5f * x * (1.f + erff(x * 0.70710678118654752440f));
}

// R13: attn LDS-BW bound (~20KB/wave-iter for 32q) + 8-way conflict on Vt
// staging writes (36-word rows). R14: 64q/wave (halves LDS per work) + Vt
// rows padded to 40 words (2-way, free).

// ---------------- Kernel A: LN1 + QKV projection ----------------
// grid (72, 3, 2) x 256. Q/K -> [n][c]; V -> TRANSPOSED [c][n].
__global__ __launch_bounds__(256) void k_ln_qkv(
    const float* __restrict__ x, const float* __restrict__ ln1w, const float* __restrict__ ln1b,
    const float* __restrict__ qw, const float* __restrict__ qb,
    const float* __restrict__ kw, const float* __restrict__ kb,
    const float* __restrict__ vw, const float* __restrict__ vb,
    short* __restrict__ Qg, short* __restrict__ Kg, short* __restrict__ Vgt) {
  int mat = blockIdx.y;
  int half = blockIdx.z;
  const float* wsrc = (mat == 0) ? qw : (mat == 1) ? kw : vw;
  const float* bsrc = (mat == 0) ? qb : (mat == 1) ? kb : vb;
  int idx = blockIdx.x * 256 + threadIdx.x;
  int b = idx / NPOS, n = idx % NPOS;
  const float* xb = x + (size_t)b * CH * NPOS + n;
  float xr[64];
  float mu = 0.f;
#pragma unroll
  for (int c = 0; c < 64; ++c) { float v = xb[c * NPOS]; xr[c] = v; mu += v; }
  mu *= (1.f / 64.f);
  float var = 0.f;
#pragma unroll
  for (int c = 0; c < 64; ++c) { float d = xr[c] - mu; var += d * d; }
  float rstd = rsqrtf(var * (1.f / 64.f) + 1e-5f);
#pragma unroll
  for (int c = 0; c < 64; ++c) xr[c] = (xr[c] - mu) * rstd * ln1w[c] + ln1b[c];
  if (mat == 2) {
    for (int o2 = 0; o2 < 4; ++o2) {
#pragma unroll
      for (int j = 0; j < 8; ++j) {
        int o = half * 32 + o2 * 8 + j;
        float acc = bsrc[o];
        const float* wrow = wsrc + o * 64;
#pragma unroll
        for (int c = 0; c < 64; ++c) acc += wrow[c] * xr[c];
        Vgt[(size_t)o * NTOT + idx] = f2bf(acc);
      }
    }
  } else {
    float kscale = (mat == 1) ? LOG2E : 1.f;
    short* outp = ((mat == 0) ? Qg : Kg) + (size_t)idx * 64 + half * 32;
    for (int o2 = 0; o2 < 4; ++o2) {
      bf16x8 v8;
#pragma unroll
      for (int j = 0; j < 8; ++j) {
        int o = half * 32 + o2 * 8 + j;
        float acc = bsrc[o];
        const float* wrow = wsrc + o * 64;
#pragma unroll
        for (int c = 0; c < 64; ++c) acc += wrow[c] * xr[c];
        v8[j] = f2bf(acc * kscale);
      }
      *(bf16x8*)(outp + o2 * 8) = v8;
    }
  }
}

// ---------------- Kernel B: MFMA flash attention, 64 q/wave ----------------
// grid (36, 2, NSPLIT) x 256. 256 q/block, 64 q/wave (4 q-tiles).
#define LDPK 80   // Kt row: 40 words
#define LDPV 80   // Vt row: 40 words (R14: was 36 -> 8-way staging conflicts)
__global__ __launch_bounds__(256) void k_attn(
    const short* __restrict__ Qg, const short* __restrict__ Kg, const short* __restrict__ Vgt,
    u32* __restrict__ PoT, float* __restrict__ Pl) {
  __shared__ __align__(16) short Kt[64 * LDPK];
  __shared__ __align__(16) short Vt[64 * LDPV];
  int b = blockIdx.y;
  int n0 = blockIdx.x * 256;
  int ks = blockIdx.z;
  int tid = threadIdx.x;
  int w = tid >> 6, lane = tid & 63;
  int L = lane & 15, quad = lane >> 4;

  bf16x8 qa[4][2];
#pragma unroll
  for (int qt = 0; qt < 4; ++qt) {
    const short* qb_ = Qg + ((size_t)(b * NPOS + n0 + w * 64 + qt * 16 + L)) * 64;
    qa[qt][0] = *(const bf16x8*)(qb_ + quad * 8);
    qa[qt][1] = *(const bf16x8*)(qb_ + 32 + quad * 8);
  }

  f32x4 o[4][4];
#pragma unroll
  for (int qt = 0; qt < 4; ++qt)
#pragma unroll
    for (int nb = 0; nb < 4; ++nb) o[qt][nb] = (f32x4){0.f, 0.f, 0.f, 0.f};
  float rl[4] = {0.f, 0.f, 0.f, 0.f};

  int c8 = tid & 7, dr = tid >> 3;
  i32x4 kr0, kr1, vr0, vr1;
  {
    int kt = ks * TILES_PER_SPLIT;
    const i32x4* src = (const i32x4*)(Kg + ((size_t)(b * NPOS + kt * 64)) * 64);
    kr0 = src[tid]; kr1 = src[tid + 256];
    const short* vbase = Vgt + (size_t)b * NPOS + kt * 64 + c8 * 8;
    vr0 = *(const i32x4*)(vbase + (size_t)dr * NTOT);
    vr1 = *(const i32x4*)(vbase + (size_t)(dr + 32) * NTOT);
  }

  for (int t = 0; t < TILES_PER_SPLIT; ++t) {
    __syncthreads();
    {
      i32x4* dst = (i32x4*)Kt;
      dst[(tid >> 3) * 10 + (tid & 7)] = kr0;
      dst[((tid + 256) >> 3) * 10 + (tid & 7)] = kr1;
      i32x4* vdst = (i32x4*)Vt;
      vdst[dr * 10 + c8] = vr0;
      vdst[(dr + 32) * 10 + c8] = vr1;
    }
    __syncthreads();
    if (t + 1 < TILES_PER_SPLIT) {
      int kt = ks * TILES_PER_SPLIT + t + 1;
      const i32x4* src = (const i32x4*)(Kg + ((size_t)(b * NPOS + kt * 64)) * 64);
      kr0 = src[tid]; kr1 = src[tid + 256];
      const short* vbase = Vgt + (size_t)b * NPOS + kt * 64 + c8 * 8;
      vr0 = *(const i32x4*)(vbase + (size_t)dr * NTOT);
      vr1 = *(const i32x4*)(vbase + (size_t)(dr + 32) * NTOT);
    }

    const i32x4* kt4 = (const i32x4*)Kt;
#pragma unroll
    for (int kti = 0; kti < 4; ++kti) {
      bf16x8 kf0 = __builtin_bit_cast(bf16x8, kt4[(kti * 16 + L) * 10 + quad]);
      bf16x8 kf1 = __builtin_bit_cast(bf16x8, kt4[(kti * 16 + L) * 10 + 4 + quad]);
      bf16x4 pp[4];
#pragma unroll
      for (int qt = 0; qt < 4; ++qt) {
        f32x4 st = {0.f, 0.f, 0.f, 0.f};
        st = __builtin_amdgcn_mfma_f32_16x16x32_bf16(kf0, qa[qt][0], st, 0, 0, 0);
        st = __builtin_amdgcn_mfma_f32_16x16x32_bf16(kf1, qa[qt][1], st, 0, 0, 0);
        float p0 = __builtin_amdgcn_exp2f(st[0]);
        float p1 = __builtin_amdgcn_exp2f(st[1]);
        float p2 = __builtin_amdgcn_exp2f(st[2]);
        float p3 = __builtin_amdgcn_exp2f(st[3]);
        rl[qt] += (p0 + p1) + (p2 + p3);
        u32 lo = __builtin_amdgcn_perm(__builtin_bit_cast(u32, p1), __builtin_bit_cast(u32, p0), 0x07060302u);
        u32 hi = __builtin_amdgcn_perm(__builtin_bit_cast(u32, p3), __builtin_bit_cast(u32, p2), 0x07060302u);
        u32 pr[2] = {lo, hi};
        pp[qt] = __builtin_bit_cast(bf16x4, pr);
      }
#pragma unroll
      for (int nb = 0; nb < 4; ++nb) {
        bf16x4 va = *(const bf16x4*)(Vt + (nb * 16 + L) * LDPV + kti * 16 + quad * 4);
#pragma unroll
        for (int qt = 0; qt < 4; ++qt)
          o[qt][nb] = __builtin_amdgcn_mfma_f32_16x16x16bf16_1k(va, pp[qt], o[qt][nb], 0, 0, 0);
      }
    }
  }

#pragma unroll
  for (int qt = 0; qt < 4; ++qt) {
    rl[qt] += __shfl_xor(rl[qt], 16);
    rl[qt] += __shfl_xor(rl[qt], 32);
  }

#pragma unroll
  for (int qt = 0; qt < 4; ++qt) {
    int qg = b * NPOS + n0 + w * 64 + qt * 16 + L;
#pragma unroll
    for (int nb = 0; nb < 4; ++nb)
#pragma unroll
      for (int ip = 0; ip < 2; ++ip) {
        u32 pk = ((u32)(unsigned short)f2bf(o[qt][nb][2 * ip + 1]) << 16) |
                 (u32)(unsigned short)f2bf(o[qt][nb][2 * ip]);
        int d32 = nb * 8 + quad * 2 + ip;
        PoT[((size_t)(ks * 32 + d32)) * NTOT + qg] = pk;
      }
    if (quad == 0) Pl[(size_t)ks * NTOT + qg] = rl[qt];
  }
}

// ---------------- Kernel C: merge + residual + LN2 + MFMA proj_in (+X2) ----------------
// grid (288) x 256.
__global__ __launch_bounds__(256) void k_res_ln2_proj(
    const float* __restrict__ x, const u32* __restrict__ PoT, const float* __restrict__ Pl,
    const float* __restrict__ ln2w, const float* __restrict__ ln2b,
    const float* __restrict__ piw,
    float* __restrict__ X2, float* __restrict__ Hbuf) {
  __shared__ float s1a[4 * 64], s2a[4 * 64];
  __shared__ __align__(16) short xn[64 * 72];
  int t = threadIdx.x;
  int w = t >> 6;
  int p = t & 63;
  int q0 = blockIdx.x * 64;
  int q = q0 + p;
  int b = q / NPOS;
  int nn = q0 % NPOS;
  int n = q % NPOS;

  float lsum = 0.f;
#pragma unroll
  for (int s = 0; s < NSPLIT; ++s) lsum += Pl[(size_t)s * NTOT + q];
  float inv = 1.f / lsum;

  const float* xb = x + (size_t)b * CH * NPOS + n;
  float xr[16];
  float s1 = 0.f, s2 = 0.f;
#pragma unroll
  for (int j2 = 0; j2 < 8; ++j2) {
    float a0 = 0.f, a1 = 0.f;
#pragma unroll
    for (int s = 0; s < NSPLIT; ++s) {
      u32 v = PoT[((size_t)(s * 32 + w * 8 + j2)) * NTOT + q];
      a0 += __builtin_bit_cast(float, v << 16);
      a1 += __builtin_bit_cast(float, v & 0xffff0000u);
    }
    int cl = 2 * j2;
    int c = w * 16 + cl;
    float v0 = xb[(size_t)c * NPOS] + a0 * inv;
    float v1 = xb[(size_t)(c + 1) * NPOS] + a1 * inv;
    xr[cl] = v0; xr[cl + 1] = v1;
    s1 += v0 + v1;
    s2 += v0 * v0 + v1 * v1;
  }
  s1a[w * 64 + p] = s1;
  s2a[w * 64 + p] = s2;
  {
    float* xo = X2 + (size_t)b * CH * NPOS + n;
#pragma unroll
    for (int cl = 0; cl < 16; ++cl) xo[(size_t)(w * 16 + cl) * NPOS] = xr[cl];
  }
  __syncthreads();
  float mu = 0.f, m2 = 0.f;
#pragma unroll
  for (int ww = 0; ww < 4; ++ww) { mu += s1a[ww * 64 + p]; m2 += s2a[ww * 64 + p]; }
  mu *= (1.f / 64.f);
  float var = m2 * (1.f / 64.f) - mu * mu;
  float rstd = rsqrtf(var + 1e-5f);
  {
    u32* xw = (u32*)xn;
#pragma unroll
    for (int j2 = 0; j2 < 8; ++j2) {
      int cl = 2 * j2, c = w * 16 + cl;
      float y0 = (xr[cl] - mu) * rstd * ln2w[c] + ln2b[c];
      float y1 = (xr[cl + 1] - mu) * rstd * ln2w[c + 1] + ln2b[c + 1];
      u32 pk = ((u32)(unsigned short)f2bf(y1) << 16) | (u32)(unsigned short)f2bf(y0);
      xw[p * 36 + w * 8 + j2] = pk;
    }
  }
  __syncthreads();
  int lane = t & 63;
  int L = lane & 15, quad = lane >> 4;
  bf16x8 a0, a1;
  {
    const float* wr = piw + (w * 16 + L) * 64 + quad * 8;
#pragma unroll
    for (int j = 0; j < 8; ++j) { a0[j] = f2bf(wr[j]); a1[j] = f2bf(wr[32 + j]); }
  }
  float* hb = Hbuf + (size_t)b * CH * NPOS + nn;
#pragma unroll
  for (int pt = 0; pt < 4; ++pt) {
    bf16x8 b0 = *(const bf16x8*)(xn + (pt * 16 + L) * 72 + quad * 8);
    bf16x8 b1 = *(const bf16x8*)(xn + (pt * 16 + L) * 72 + 32 + quad * 8);
    f32x4 acc = {0.f, 0.f, 0.f, 0.f};
    acc = __builtin_amdgcn_mfma_f32_16x16x32_bf16(a0, b0, acc, 0, 0, 0);
    acc = __builtin_amdgcn_mfma_f32_16x16x32_bf16(a1, b1, acc, 0, 0, 0);
#pragma unroll
    for (int i = 0; i < 4; ++i)
      hb[(size_t)(w * 16 + quad * 4 + i) * NPOS + pt * 16 + L] = acc[i];
  }
}

// ---------------- Kernel D: per-patch spectral filter ----------------
// grid (288) x 64.
__global__ __launch_bounds__(64) void k_fft(float* __restrict__ Hbuf, const float* __restrict__ fftw) {
  int idx = blockIdx.x * 64 + threadIdx.x;
  int wb = idx % 12;
  int t = idx / 12;
  int hb = t % 12;
  int t2 = t / 12;
  int c = t2 % 64;
  int b = t2 / 64;
  float* base = Hbuf + (size_t)(b * CH + c) * NPOS + (hb * 8) * 96 + wb * 8;
  const float r = 0.70710678118654752440f;
  const float CO[8] = {1.f, r, 0.f, -r, -1.f, -r, 0.f, r};
  const float SI[8] = {0.f, r, 1.f, r, 0.f, -r, -1.f, -r};
  float Ar[8][5], Ai[8][5];
#pragma unroll
  for (int p = 0; p < 8; ++p) {
    f32x4 ra = *(const f32x4*)(base + p * 96);
    f32x4 rb = *(const f32x4*)(base + p * 96 + 4);
    float row[8] = {ra[0], ra[1], ra[2], ra[3], rb[0], rb[1], rb[2], rb[3]};
#pragma unroll
    for (int v = 0; v < 5; ++v) {
      float sr = 0.f, si = 0.f;
#pragma unroll
      for (int q = 0; q < 8; ++q) {
        int k = (q * v) & 7;
        sr += row[q] * CO[k];
        si -= row[q] * SI[k];
      }
      Ar[p][v] = sr;
      Ai[p][v] = si;
    }
  }
  const float* wp = fftw + c * 40;
#pragma unroll
  for (int v = 0; v < 5; ++v) {
    float Br[8], Bi[8];
#pragma unroll
    for (int u = 0; u < 8; ++u) {
      float cr = 0.f, ci = 0.f;
#pragma unroll
      for (int p = 0; p < 8; ++p) {
        int k = (p * u) & 7;
        float cc = CO[k], ss = SI[k];
        cr += Ar[p][v] * cc + Ai[p][v] * ss;
        ci += Ai[p][v] * cc - Ar[p][v] * ss;
      }
      float wv = wp[u * 5 + v];
      Br[u] = cr * wv;
      Bi[u] = ci * wv;
    }
#pragma unroll
    for (int p = 0; p < 8; ++p) {
      float yr = 0.f, yi = 0.f;
#pragma unroll
      for (int u = 0; u < 8; ++u) {
        int k = (p * u) & 7;
        float cc = CO[k], ss = SI[k];
        yr += Br[u] * cc - Bi[u] * ss;
        yi += Bi[u] * cc + Br[u] * ss;
      }
      Ar[p][v] = yr * 0.125f;
      Ai[p][v] = yi * 0.125f;
    }
  }
#pragma unroll
  for (int p = 0; p < 8; ++p) {
    float outv[8];
#pragma unroll
    for (int q = 0; q < 8; ++q) {
      float acc = Ar[p][0] + ((q & 1) ? -Ar[p][4] : Ar[p][4]);
#pragma unroll
      for (int v = 1; v < 4; ++v) {
        int k = (q * v) & 7;
        acc += 2.f * (Ar[p][v] * CO[k] - Ai[p][v] * SI[k]);
      }
      outv[q] = acc * 0.125f;
    }
    f32x4 wa = {outv[0], outv[1], outv[2], outv[3]};
    f32x4 wb2 = {outv[4], outv[5], outv[6], outv[7]};
    *(f32x4*)(base + p * 96) = wa;
    *(f32x4*)(base + p * 96 + 4) = wb2;
  }
}

// ---------------- Kernel E1: dwconv3x3 + gelu-gate -> G ----------------
// grid (72, 32) x 256.
__global__ __launch_bounds__(256) void k_dw_gate(
    const float* __restrict__ Hbuf, const float* __restrict__ dww,
    float* __restrict__ G) {
  int cc = blockIdx.y;
  int q = blockIdx.x * 256 + threadIdx.x;
  int b = q / NPOS, n = q % NPOS;
  int y = n / 96, xx = n % 96;
  const float* h1 = Hbuf + (size_t)(b * CH + cc) * NPOS;
  const float* h2 = Hbuf + (size_t)(b * CH + cc + 32) * NPOS;
  float wd1[9], wd2[9];
#pragma unroll
  for (int ki = 0; ki < 9; ++ki) { wd1[ki] = dww[cc * 9 + ki]; wd2[ki] = dww[(cc + 32) * 9 + ki]; }
  float d1 = 0.f, d2 = 0.f;
  for (int dy = -1; dy <= 1; ++dy) {
    int yy = y + dy;
    if (yy < 0 || yy >= 96) continue;
    for (int dx = -1; dx <= 1; ++dx) {
      int xv = xx + dx;
      if (xv < 0 || xv >= 96) continue;
      int ki = (dy + 1) * 3 + (dx + 1);
      d1 += h1[yy * 96 + xv] * wd1[ki];
      d2 += h2[yy * 96 + xv] * wd2[ki];
    }
  }
  G[(size_t)cc * NTOT + q] = gelu_exact(d1) * d2;
}

// ---------------- Kernel E2: proj_out + residual ----------------
// grid (72, 8) x 256.
__global__ __launch_bounds__(256) void k_proj_out(
    const float* __restrict__ G, const float* __restrict__ poww,
    const float* __restrict__ X2, float* __restrict__ out) {
  int og = blockIdx.y;
  int q = blockIdx.x * 256 + threadIdx.x;
  int b = q / NPOS, n = q % NPOS;
  float g[32];
#pragma unroll
  for (int cg = 0; cg < 32; ++cg) g[cg] = G[(size_t)cg * NTOT + q];
  const float* xr = X2 + (size_t)b * CH * NPOS + n;
  float* ob = out + (size_t)b * CH * NPOS + n;
#pragma unroll
  for (int j = 0; j < 8; ++j) {
    int oc = og * 8 + j;
    const float* prow = poww + oc * 32;
    float acc = xr[(size_t)oc * NPOS];
#pragma unroll
    for (int cg = 0; cg < 32; ++cg) acc += prow[cg] * g[cg];
    ob[(size_t)oc * NPOS] = acc;
  }
}

extern "C" void kernel_launch(void* const* d_in, const int* in_sizes, int n_in,
                              void* d_out, int out_size, void* d_ws, size_t ws_size,
                              hipStream_t stream) {
  const float* x    = (const float*)d_in[0];
  const float* ln1w = (const float*)d_in[1];
  const float* ln1b = (const float*)d_in[2];
  const float* ln2w = (const float*)d_in[3];
  const float* ln2b = (const float*)d_in[4];
  const float* qw   = (const float*)d_in[5];
  const float* qb   = (const float*)d_in[6];
  const float* kw   = (const float*)d_in[7];
  const float* kb   = (const float*)d_in[8];
  const float* vw   = (const float*)d_in[9];
  const float* vb   = (const float*)d_in[10];
  const float* fftw = (const float*)d_in[11];
  const float* piw  = (const float*)d_in[12];
  const float* dww  = (const float*)d_in[13];
  const float* poww = (const float*)d_in[14];

  short* Qg  = (short*)d_ws;
  short* Kg  = Qg + (size_t)NTOT * 64;
  short* Vgt = Kg + (size_t)NTOT * 64;
  u32*   PoT = (u32*)(Vgt + (size_t)NTOT * 64);
  float* Pl  = (float*)(PoT + (size_t)NSPLIT * 32 * NTOT);
  float* X2  = Pl + (size_t)NSPLIT * NTOT;
  float* Hbuf = X2 + (size_t)NTOT * 64;
  float* G   = Hbuf + (size_t)NTOT * 64;

  k_ln_qkv<<<dim3(72, 3, 2), 256, 0, stream>>>(x, ln1w, ln1b, qw, qb, kw, kb, vw, vb, Qg, Kg, Vgt);
  k_attn<<<dim3(36, 2, NSPLIT), 256, 0, stream>>>(Qg, Kg, Vgt, PoT, Pl);
  k_res_ln2_proj<<<dim3(288), 256, 0, stream>>>(x, PoT, Pl, ln2w, ln2b, piw, X2, Hbuf);
  k_fft<<<dim3(288), 64, 0, stream>>>(Hbuf, fftw);
  k_dw_gate<<<dim3(72, 32), 256, 0, stream>>>(Hbuf, dww, G);
  k_proj_out<<<dim3(72, 8), 256, 0, stream>>>(G, poww, X2, (float*)d_out);
}

// Round 15
// 221.881 us; speedup vs baseline: 1.0034x; 1.0034x over previous
//
#include <hip/hip_runtime.h>
#include <hip/hip_bf16.h>
#include <math.h>

#define CH 64
#define NPOS 9216   // 96*96
#define NTOT 18432  // 2*9216
#define NSPLIT 8
#define TILES_PER_SPLIT 18   // 144/8
#define LOG2E 1.4426950408889634f

typedef short bf16x8 __attribute__((ext_vector_type(8)));
typedef short bf16x4 __attribute__((ext_vector_type(4)));
typedef float f32x4 __attribute__((ext_vector_type(4)));
typedef int   i32x4 __attribute__((ext_vector_type(4)));
typedef unsigned int u32;

__device__ __forceinline__ float bf2f(short s) {
  unsigned int u = ((unsigned int)(unsigned short)s) << 16;
  return __builtin_bit_cast(float, u);
}
__device__ __forceinline__ short f2bf(float f) {
  unsigned int u = __builtin_bit_cast(unsigned int, f);
  unsigned int r = (u + 0x7fffu + ((u >> 16) & 1u)) >> 16;  // RNE
  return (short)r;
}
__device__ __forceinline__ float gelu_exact(float x) {
  return 0.5f * x * (1.f + erff(x * 0.70710678118654752440f));
}

// R14 regressed: 64q/wave -> VGPR 144, Occ 8%, and Vt-40 made V reads 4-way.
// R15: attn reverted to exact R13 (78us proven). C -> 512-thr blocks (2x waves).
// E2 -> (72,2) 32oc/thread (G read 2x not 8x).

// ---------------- Kernel A: LN1 + QKV projection ----------------
// grid (72, 3, 2) x 256. Q/K -> [n][c]; V -> TRANSPOSED [c][n].
__global__ __launch_bounds__(256) void k_ln_qkv(
    const float* __restrict__ x, const float* __restrict__ ln1w, const float* __restrict__ ln1b,
    const float* __restrict__ qw, const float* __restrict__ qb,
    const float* __restrict__ kw, const float* __restrict__ kb,
    const float* __restrict__ vw, const float* __restrict__ vb,
    short* __restrict__ Qg, short* __restrict__ Kg, short* __restrict__ Vgt) {
  int mat = blockIdx.y;
  int half = blockIdx.z;
  const float* wsrc = (mat == 0) ? qw : (mat == 1) ? kw : vw;
  const float* bsrc = (mat == 0) ? qb : (mat == 1) ? kb : vb;
  int idx = blockIdx.x * 256 + threadIdx.x;
  int b = idx / NPOS, n = idx % NPOS;
  const float* xb = x + (size_t)b * CH * NPOS + n;
  float xr[64];
  float mu = 0.f;
#pragma unroll
  for (int c = 0; c < 64; ++c) { float v = xb[c * NPOS]; xr[c] = v; mu += v; }
  mu *= (1.f / 64.f);
  float var = 0.f;
#pragma unroll
  for (int c = 0; c < 64; ++c) { float d = xr[c] - mu; var += d * d; }
  float rstd = rsqrtf(var * (1.f / 64.f) + 1e-5f);
#pragma unroll
  for (int c = 0; c < 64; ++c) xr[c] = (xr[c] - mu) * rstd * ln1w[c] + ln1b[c];
  if (mat == 2) {
    for (int o2 = 0; o2 < 4; ++o2) {
#pragma unroll
      for (int j = 0; j < 8; ++j) {
        int o = half * 32 + o2 * 8 + j;
        float acc = bsrc[o];
        const float* wrow = wsrc + o * 64;
#pragma unroll
        for (int c = 0; c < 64; ++c) acc += wrow[c] * xr[c];
        Vgt[(size_t)o * NTOT + idx] = f2bf(acc);
      }
    }
  } else {
    float kscale = (mat == 1) ? LOG2E : 1.f;
    short* outp = ((mat == 0) ? Qg : Kg) + (size_t)idx * 64 + half * 32;
    for (int o2 = 0; o2 < 4; ++o2) {
      bf16x8 v8;
#pragma unroll
      for (int j = 0; j < 8; ++j) {
        int o = half * 32 + o2 * 8 + j;
        float acc = bsrc[o];
        const float* wrow = wsrc + o * 64;
#pragma unroll
        for (int c = 0; c < 64; ++c) acc += wrow[c] * xr[c];
        v8[j] = f2bf(acc * kscale);
      }
      *(bf16x8*)(outp + o2 * 8) = v8;
    }
  }
}

// ---------------- Kernel B: MFMA flash attention (exact R13) ----------------
// grid (72, 2, NSPLIT) x 256. 128 q/block, 32 q/wave.
#define LDPK 80
#define LDP  72
__global__ __launch_bounds__(256) void k_attn(
    const short* __restrict__ Qg, const short* __restrict__ Kg, const short* __restrict__ Vgt,
    u32* __restrict__ PoT, float* __restrict__ Pl) {
  __shared__ __align__(16) short Kt[64 * LDPK];
  __shared__ __align__(16) short Vt[64 * LDP];
  int b = blockIdx.y;
  int n0 = blockIdx.x * 128;
  int ks = blockIdx.z;
  int tid = threadIdx.x;
  int w = tid >> 6, lane = tid & 63;
  int L = lane & 15, quad = lane >> 4;

  bf16x8 qa[2][2];
#pragma unroll
  for (int qt = 0; qt < 2; ++qt) {
    const short* qb_ = Qg + ((size_t)(b * NPOS + n0 + w * 32 + qt * 16 + L)) * 64;
    qa[qt][0] = *(const bf16x8*)(qb_ + quad * 8);
    qa[qt][1] = *(const bf16x8*)(qb_ + 32 + quad * 8);
  }

  f32x4 o[2][4];
#pragma unroll
  for (int qt = 0; qt < 2; ++qt)
#pragma unroll
    for (int nb = 0; nb < 4; ++nb) o[qt][nb] = (f32x4){0.f, 0.f, 0.f, 0.f};
  float rl[2] = {0.f, 0.f};

  int c8 = tid & 7, dr = tid >> 3;
  i32x4 kr0, kr1, vr0, vr1;
  {
    int kt = ks * TILES_PER_SPLIT;
    const i32x4* src = (const i32x4*)(Kg + ((size_t)(b * NPOS + kt * 64)) * 64);
    kr0 = src[tid]; kr1 = src[tid + 256];
    const short* vbase = Vgt + (size_t)b * NPOS + kt * 64 + c8 * 8;
    vr0 = *(const i32x4*)(vbase + (size_t)dr * NTOT);
    vr1 = *(const i32x4*)(vbase + (size_t)(dr + 32) * NTOT);
  }

  for (int t = 0; t < TILES_PER_SPLIT; ++t) {
    __syncthreads();
    {
      i32x4* dst = (i32x4*)Kt;
      dst[(tid >> 3) * 10 + (tid & 7)] = kr0;
      dst[((tid + 256) >> 3) * 10 + (tid & 7)] = kr1;
      i32x4* vdst = (i32x4*)Vt;
      vdst[dr * 9 + c8] = vr0;
      vdst[(dr + 32) * 9 + c8] = vr1;
    }
    __syncthreads();
    if (t + 1 < TILES_PER_SPLIT) {
      int kt = ks * TILES_PER_SPLIT + t + 1;
      const i32x4* src = (const i32x4*)(Kg + ((size_t)(b * NPOS + kt * 64)) * 64);
      kr0 = src[tid]; kr1 = src[tid + 256];
      const short* vbase = Vgt + (size_t)b * NPOS + kt * 64 + c8 * 8;
      vr0 = *(const i32x4*)(vbase + (size_t)dr * NTOT);
      vr1 = *(const i32x4*)(vbase + (size_t)(dr + 32) * NTOT);
    }

    const i32x4* kt4 = (const i32x4*)Kt;
#pragma unroll
    for (int kti = 0; kti < 4; ++kti) {
      bf16x8 kf0 = __builtin_bit_cast(bf16x8, kt4[(kti * 16 + L) * 10 + quad]);
      bf16x8 kf1 = __builtin_bit_cast(bf16x8, kt4[(kti * 16 + L) * 10 + 4 + quad]);
      bf16x4 pp[2];
#pragma unroll
      for (int qt = 0; qt < 2; ++qt) {
        f32x4 st = {0.f, 0.f, 0.f, 0.f};
        st = __builtin_amdgcn_mfma_f32_16x16x32_bf16(kf0, qa[qt][0], st, 0, 0, 0);
        st = __builtin_amdgcn_mfma_f32_16x16x32_bf16(kf1, qa[qt][1], st, 0, 0, 0);
        float p0 = __builtin_amdgcn_exp2f(st[0]);
        float p1 = __builtin_amdgcn_exp2f(st[1]);
        float p2 = __builtin_amdgcn_exp2f(st[2]);
        float p3 = __builtin_amdgcn_exp2f(st[3]);
        rl[qt] += (p0 + p1) + (p2 + p3);
        u32 lo = __builtin_amdgcn_perm(__builtin_bit_cast(u32, p1), __builtin_bit_cast(u32, p0), 0x07060302u);
        u32 hi = __builtin_amdgcn_perm(__builtin_bit_cast(u32, p3), __builtin_bit_cast(u32, p2), 0x07060302u);
        u32 pr[2] = {lo, hi};
        pp[qt] = __builtin_bit_cast(bf16x4, pr);
      }
#pragma unroll
      for (int nb = 0; nb < 4; ++nb) {
        bf16x4 va = *(const bf16x4*)(Vt + (nb * 16 + L) * LDP + kti * 16 + quad * 4);
#pragma unroll
        for (int qt = 0; qt < 2; ++qt)
          o[qt][nb] = __builtin_amdgcn_mfma_f32_16x16x16bf16_1k(va, pp[qt], o[qt][nb], 0, 0, 0);
      }
    }
  }

#pragma unroll
  for (int qt = 0; qt < 2; ++qt) {
    rl[qt] += __shfl_xor(rl[qt], 16);
    rl[qt] += __shfl_xor(rl[qt], 32);
  }

#pragma unroll
  for (int qt = 0; qt < 2; ++qt) {
    int qg = b * NPOS + n0 + w * 32 + qt * 16 + L;
#pragma unroll
    for (int nb = 0; nb < 4; ++nb)
#pragma unroll
      for (int ip = 0; ip < 2; ++ip) {
        u32 pk = ((u32)(unsigned short)f2bf(o[qt][nb][2 * ip + 1]) << 16) |
                 (u32)(unsigned short)f2bf(o[qt][nb][2 * ip]);
        int d32 = nb * 8 + quad * 2 + ip;
        PoT[((size_t)(ks * 32 + d32)) * NTOT + qg] = pk;
      }
    if (quad == 0) Pl[(size_t)ks * NTOT + qg] = rl[qt];
  }
}

// ---------------- Kernel C: merge + residual + LN2 + MFMA proj_in (+X2) ----------------
// grid (288) x 512. 8 waves: phase1 = 8 ch/thread merge+LN; phase2 = MFMA, 2 tiles/wave.
__global__ __launch_bounds__(512) void k_res_ln2_proj(
    const float* __restrict__ x, const u32* __restrict__ PoT, const float* __restrict__ Pl,
    const float* __restrict__ ln2w, const float* __restrict__ ln2b,
    const float* __restrict__ piw,
    float* __restrict__ X2, float* __restrict__ Hbuf) {
  __shared__ float s1a[8 * 64], s2a[8 * 64];
  __shared__ __align__(16) short xn[64 * 72];
  int t = threadIdx.x;
  int w = t >> 6;       // 0..7: channel group of 8
  int p = t & 63;
  int q0 = blockIdx.x * 64;
  int q = q0 + p;
  int b = q / NPOS;
  int nn = q0 % NPOS;
  int n = q % NPOS;

  float lsum = 0.f;
#pragma unroll
  for (int s = 0; s < NSPLIT; ++s) lsum += Pl[(size_t)s * NTOT + q];
  float inv = 1.f / lsum;

  const float* xb = x + (size_t)b * CH * NPOS + n;
  float xr[8];
  float s1 = 0.f, s2 = 0.f;
#pragma unroll
  for (int j2 = 0; j2 < 4; ++j2) {
    int c = w * 8 + 2 * j2;
    int d32 = ((c >> 4) << 3) | (((c >> 2) & 3) << 1) | ((c >> 1) & 1);
    float a0 = 0.f, a1 = 0.f;
#pragma unroll
    for (int s = 0; s < NSPLIT; ++s) {
      u32 v = PoT[((size_t)(s * 32 + d32)) * NTOT + q];
      a0 += __builtin_bit_cast(float, v << 16);
      a1 += __builtin_bit_cast(float, v & 0xffff0000u);
    }
    float v0 = xb[(size_t)c * NPOS] + a0 * inv;
    float v1 = xb[(size_t)(c + 1) * NPOS] + a1 * inv;
    xr[2 * j2] = v0; xr[2 * j2 + 1] = v1;
    s1 += v0 + v1;
    s2 += v0 * v0 + v1 * v1;
  }
  s1a[w * 64 + p] = s1;
  s2a[w * 64 + p] = s2;
  {
    float* xo = X2 + (size_t)b * CH * NPOS + n;
#pragma unroll
    for (int cl = 0; cl < 8; ++cl) xo[(size_t)(w * 8 + cl) * NPOS] = xr[cl];
  }
  __syncthreads();
  float mu = 0.f, m2 = 0.f;
#pragma unroll
  for (int ww = 0; ww < 8; ++ww) { mu += s1a[ww * 64 + p]; m2 += s2a[ww * 64 + p]; }
  mu *= (1.f / 64.f);
  float var = m2 * (1.f / 64.f) - mu * mu;
  float rstd = rsqrtf(var + 1e-5f);
  {
    u32* xw = (u32*)xn;
#pragma unroll
    for (int j2 = 0; j2 < 4; ++j2) {
      int c = w * 8 + 2 * j2;
      float y0 = (xr[2 * j2] - mu) * rstd * ln2w[c] + ln2b[c];
      float y1 = (xr[2 * j2 + 1] - mu) * rstd * ln2w[c + 1] + ln2b[c + 1];
      u32 pk = ((u32)(unsigned short)f2bf(y1) << 16) | (u32)(unsigned short)f2bf(y0);
      xw[p * 36 + w * 4 + j2] = pk;
    }
  }
  __syncthreads();
  // Phase 2: 16 tiles (4 oc-tiles x 4 pos-tiles) over 8 waves -> 2 tiles/wave.
  int lane = t & 63;
  int L = lane & 15, quad = lane >> 4;
  float* hb = Hbuf + (size_t)b * CH * NPOS + nn;
#pragma unroll
  for (int ti = 0; ti < 2; ++ti) {
    int tile = w * 2 + ti;
    int oct = tile >> 2, pt = tile & 3;
    bf16x8 a0, a1;
    const float* wr = piw + (oct * 16 + L) * 64 + quad * 8;
#pragma unroll
    for (int j = 0; j < 8; ++j) { a0[j] = f2bf(wr[j]); a1[j] = f2bf(wr[32 + j]); }
    bf16x8 b0 = *(const bf16x8*)(xn + (pt * 16 + L) * 72 + quad * 8);
    bf16x8 b1 = *(const bf16x8*)(xn + (pt * 16 + L) * 72 + 32 + quad * 8);
    f32x4 acc = {0.f, 0.f, 0.f, 0.f};
    acc = __builtin_amdgcn_mfma_f32_16x16x32_bf16(a0, b0, acc, 0, 0, 0);
    acc = __builtin_amdgcn_mfma_f32_16x16x32_bf16(a1, b1, acc, 0, 0, 0);
#pragma unroll
    for (int ii = 0; ii < 4; ++ii)
      hb[(size_t)(oct * 16 + quad * 4 + ii) * NPOS + pt * 16 + L] = acc[ii];
  }
}

// ---------------- Kernel D: per-patch spectral filter ----------------
// grid (288) x 64.
__global__ __launch_bounds__(64) void k_fft(float* __restrict__ Hbuf, const float* __restrict__ fftw) {
  int idx = blockIdx.x * 64 + threadIdx.x;
  int wb = idx % 12;
  int t = idx / 12;
  int hb = t % 12;
  int t2 = t / 12;
  int c = t2 % 64;
  int b = t2 / 64;
  float* base = Hbuf + (size_t)(b * CH + c) * NPOS + (hb * 8) * 96 + wb * 8;
  const float r = 0.70710678118654752440f;
  const float CO[8] = {1.f, r, 0.f, -r, -1.f, -r, 0.f, r};
  const float SI[8] = {0.f, r, 1.f, r, 0.f, -r, -1.f, -r};
  float Ar[8][5], Ai[8][5];
#pragma unroll
  for (int p = 0; p < 8; ++p) {
    f32x4 ra = *(const f32x4*)(base + p * 96);
    f32x4 rb = *(const f32x4*)(base + p * 96 + 4);
    float row[8] = {ra[0], ra[1], ra[2], ra[3], rb[0], rb[1], rb[2], rb[3]};
#pragma unroll
    for (int v = 0; v < 5; ++v) {
      float sr = 0.f, si = 0.f;
#pragma unroll
      for (int q = 0; q < 8; ++q) {
        int k = (q * v) & 7;
        sr += row[q] * CO[k];
        si -= row[q] * SI[k];
      }
      Ar[p][v] = sr;
      Ai[p][v] = si;
    }
  }
  const float* wp = fftw + c * 40;
#pragma unroll
  for (int v = 0; v < 5; ++v) {
    float Br[8], Bi[8];
#pragma unroll
    for (int u = 0; u < 8; ++u) {
      float cr = 0.f, ci = 0.f;
#pragma unroll
      for (int p = 0; p < 8; ++p) {
        int k = (p * u) & 7;
        float cc = CO[k], ss = SI[k];
        cr += Ar[p][v] * cc + Ai[p][v] * ss;
        ci += Ai[p][v] * cc - Ar[p][v] * ss;
      }
      float wv = wp[u * 5 + v];
      Br[u] = cr * wv;
      Bi[u] = ci * wv;
    }
#pragma unroll
    for (int p = 0; p < 8; ++p) {
      float yr = 0.f, yi = 0.f;
#pragma unroll
      for (int u = 0; u < 8; ++u) {
        int k = (p * u) & 7;
        float cc = CO[k], ss = SI[k];
        yr += Br[u] * cc - Bi[u] * ss;
        yi += Bi[u] * cc + Br[u] * ss;
      }
      Ar[p][v] = yr * 0.125f;
      Ai[p][v] = yi * 0.125f;
    }
  }
#pragma unroll
  for (int p = 0; p < 8; ++p) {
    float outv[8];
#pragma unroll
    for (int q = 0; q < 8; ++q) {
      float acc = Ar[p][0] + ((q & 1) ? -Ar[p][4] : Ar[p][4]);
#pragma unroll
      for (int v = 1; v < 4; ++v) {
        int k = (q * v) & 7;
        acc += 2.f * (Ar[p][v] * CO[k] - Ai[p][v] * SI[k]);
      }
      outv[q] = acc * 0.125f;
    }
    f32x4 wa = {outv[0], outv[1], outv[2], outv[3]};
    f32x4 wb2 = {outv[4], outv[5], outv[6], outv[7]};
    *(f32x4*)(base + p * 96) = wa;
    *(f32x4*)(base + p * 96 + 4) = wb2;
  }
}

// ---------------- Kernel E1: dwconv3x3 + gelu-gate -> G ----------------
// grid (72, 32) x 256.
__global__ __launch_bounds__(256) void k_dw_gate(
    const float* __restrict__ Hbuf, const float* __restrict__ dww,
    float* __restrict__ G) {
  int cc = blockIdx.y;
  int q = blockIdx.x * 256 + threadIdx.x;
  int b = q / NPOS, n = q % NPOS;
  int y = n / 96, xx = n % 96;
  const float* h1 = Hbuf + (size_t)(b * CH + cc) * NPOS;
  const float* h2 = Hbuf + (size_t)(b * CH + cc + 32) * NPOS;
  float wd1[9], wd2[9];
#pragma unroll
  for (int ki = 0; ki < 9; ++ki) { wd1[ki] = dww[cc * 9 + ki]; wd2[ki] = dww[(cc + 32) * 9 + ki]; }
  float d1 = 0.f, d2 = 0.f;
  for (int dy = -1; dy <= 1; ++dy) {
    int yy = y + dy;
    if (yy < 0 || yy >= 96) continue;
    for (int dx = -1; dx <= 1; ++dx) {
      int xv = xx + dx;
      if (xv < 0 || xv >= 96) continue;
      int ki = (dy + 1) * 3 + (dx + 1);
      d1 += h1[yy * 96 + xv] * wd1[ki];
      d2 += h2[yy * 96 + xv] * wd2[ki];
    }
  }
  G[(size_t)cc * NTOT + q] = gelu_exact(d1) * d2;
}

// ---------------- Kernel E2: proj_out + residual ----------------
// grid (72, 2) x 256. 32 oc/thread; G read once per half.
__global__ __launch_bounds__(256) void k_proj_out(
    const float* __restrict__ G, const float* __restrict__ poww,
    const float* __restrict__ X2, float* __restrict__ out) {
  int half = blockIdx.y;
  int q = blockIdx.x * 256 + threadIdx.x;
  int b = q / NPOS, n = q % NPOS;
  float g[32];
#pragma unroll
  for (int cg = 0; cg < 32; ++cg) g[cg] = G[(size_t)cg * NTOT + q];
  const float* xr = X2 + (size_t)b * CH * NPOS + (size_t)half * 32 * NPOS + n;
  float* ob = out + (size_t)b * CH * NPOS + (size_t)half * 32 * NPOS + n;
  for (int oo = 0; oo < 32; ++oo) {
    int oc = half * 32 + oo;
    const float* prow = poww + oc * 32;
    float acc = xr[(size_t)oo * NPOS];
#pragma unroll
    for (int cg = 0; cg < 32; ++cg) acc += prow[cg] * g[cg];
    ob[(size_t)oo * NPOS] = acc;
  }
}

extern "C" void kernel_launch(void* const* d_in, const int* in_sizes, int n_in,
                              void* d_out, int out_size, void* d_ws, size_t ws_size,
                              hipStream_t stream) {
  const float* x    = (const float*)d_in[0];
  const float* ln1w = (const float*)d_in[1];
  const float* ln1b = (const float*)d_in[2];
  const float* ln2w = (const float*)d_in[3];
  const float* ln2b = (const float*)d_in[4];
  const float* qw   = (const float*)d_in[5];
  const float* qb   = (const float*)d_in[6];
  const float* kw   = (const float*)d_in[7];
  const float* kb   = (const float*)d_in[8];
  const float* vw   = (const float*)d_in[9];
  const float* vb   = (const float*)d_in[10];
  const float* fftw = (const float*)d_in[11];
  const float* piw  = (const float*)d_in[12];
  const float* dww  = (const float*)d_in[13];
  const float* poww = (const float*)d_in[14];

  short* Qg  = (short*)d_ws;
  short* Kg  = Qg + (size_t)NTOT * 64;
  short* Vgt = Kg + (size_t)NTOT * 64;
  u32*   PoT = (u32*)(Vgt + (size_t)NTOT * 64);
  float* Pl  = (float*)(PoT + (size_t)NSPLIT * 32 * NTOT);
  float* X2  = Pl + (size_t)NSPLIT * NTOT;
  float* Hbuf = X2 + (size_t)NTOT * 64;
  float* G   = Hbuf + (size_t)NTOT * 64;

  k_ln_qkv<<<dim3(72, 3, 2), 256, 0, stream>>>(x, ln1w, ln1b, qw, qb, kw, kb, vw, vb, Qg, Kg, Vgt);
  k_attn<<<dim3(72, 2, NSPLIT), 256, 0, stream>>>(Qg, Kg, Vgt, PoT, Pl);
  k_res_ln2_proj<<<dim3(288), 512, 0, stream>>>(x, PoT, Pl, ln2w, ln2b, piw, X2, Hbuf);
  k_fft<<<dim3(288), 64, 0, stream>>>(Hbuf, fftw);
  k_dw_gate<<<dim3(72, 32), 256, 0, stream>>>(Hbuf, dww, G);
  k_proj_out<<<dim3(72, 2), 256, 0, stream>>>(G, poww, X2, (float*)d_out);
}

// Round 16
// 215.598 us; speedup vs baseline: 1.0326x; 1.0291x over previous
//
#include <hip/hip_runtime.h>
#include <hip/hip_bf16.h>
#include <math.h>

#define CH 64
#define NPOS 9216   // 96*96
#define NTOT 18432  // 2*9216
#define NSPLIT 8
#define TILES_PER_SPLIT 18   // 144/8
#define LOG2E 1.4426950408889634f

typedef short bf16x8 __attribute__((ext_vector_type(8)));
typedef short bf16x4 __attribute__((ext_vector_type(4)));
typedef float f32x4 __attribute__((ext_vector_type(4)));
typedef int   i32x4 __attribute__((ext_vector_type(4)));
typedef unsigned int u32;

__device__ __forceinline__ float bf2f(short s) {
  unsigned int u = ((unsigned int)(unsigned short)s) << 16;
  return __builtin_bit_cast(float, u);
}
__device__ __forceinline__ short f2bf(float f) {
  unsigned int u = __builtin_bit_cast(unsigned int, f);
  unsigned int r = (u + 0x7fffu + ((u >> 16) & 1u)) >> 16;  // RNE
  return (short)r;
}
__device__ __forceinline__ float gelu_exact(float x) {
  return 0.5f * x * (1.f + erff(x * 0.70710678118654752440f));
}

// R15: C-512 and E2-(72,2) regressed the tail (+14us) -> ALL kernels restored
// to exact R13 (209us proven). R16 single change: attn inner loop stage-batched
// (all QK MFMAs -> all exp2 -> all PV MFMAs) to expose ILP across the
// QK->exp->PV dependency chain. Same fp order, bit-identical result.

// ---------------- Kernel A: LN1 + QKV projection ----------------
// grid (72, 3, 2) x 256. Q/K -> [n][c]; V -> TRANSPOSED [c][n].
__global__ __launch_bounds__(256) void k_ln_qkv(
    const float* __restrict__ x, const float* __restrict__ ln1w, const float* __restrict__ ln1b,
    const float* __restrict__ qw, const float* __restrict__ qb,
    const float* __restrict__ kw, const float* __restrict__ kb,
    const float* __restrict__ vw, const float* __restrict__ vb,
    short* __restrict__ Qg, short* __restrict__ Kg, short* __restrict__ Vgt) {
  int mat = blockIdx.y;
  int half = blockIdx.z;
  const float* wsrc = (mat == 0) ? qw : (mat == 1) ? kw : vw;
  const float* bsrc = (mat == 0) ? qb : (mat == 1) ? kb : vb;
  int idx = blockIdx.x * 256 + threadIdx.x;
  int b = idx / NPOS, n = idx % NPOS;
  const float* xb = x + (size_t)b * CH * NPOS + n;
  float xr[64];
  float mu = 0.f;
#pragma unroll
  for (int c = 0; c < 64; ++c) { float v = xb[c * NPOS]; xr[c] = v; mu += v; }
  mu *= (1.f / 64.f);
  float var = 0.f;
#pragma unroll
  for (int c = 0; c < 64; ++c) { float d = xr[c] - mu; var += d * d; }
  float rstd = rsqrtf(var * (1.f / 64.f) + 1e-5f);
#pragma unroll
  for (int c = 0; c < 64; ++c) xr[c] = (xr[c] - mu) * rstd * ln1w[c] + ln1b[c];
  if (mat == 2) {
    for (int o2 = 0; o2 < 4; ++o2) {
#pragma unroll
      for (int j = 0; j < 8; ++j) {
        int o = half * 32 + o2 * 8 + j;
        float acc = bsrc[o];
        const float* wrow = wsrc + o * 64;
#pragma unroll
        for (int c = 0; c < 64; ++c) acc += wrow[c] * xr[c];
        Vgt[(size_t)o * NTOT + idx] = f2bf(acc);
      }
    }
  } else {
    float kscale = (mat == 1) ? LOG2E : 1.f;
    short* outp = ((mat == 0) ? Qg : Kg) + (size_t)idx * 64 + half * 32;
    for (int o2 = 0; o2 < 4; ++o2) {
      bf16x8 v8;
#pragma unroll
      for (int j = 0; j < 8; ++j) {
        int o = half * 32 + o2 * 8 + j;
        float acc = bsrc[o];
        const float* wrow = wsrc + o * 64;
#pragma unroll
        for (int c = 0; c < 64; ++c) acc += wrow[c] * xr[c];
        v8[j] = f2bf(acc * kscale);
      }
      *(bf16x8*)(outp + o2 * 8) = v8;
    }
  }
}

// ---------------- Kernel B: MFMA flash attention (R13 + stage-batched) ----------------
// grid (72, 2, NSPLIT) x 256. 128 q/block, 32 q/wave.
#define LDPK 80
#define LDP  72
__global__ __launch_bounds__(256) void k_attn(
    const short* __restrict__ Qg, const short* __restrict__ Kg, const short* __restrict__ Vgt,
    u32* __restrict__ PoT, float* __restrict__ Pl) {
  __shared__ __align__(16) short Kt[64 * LDPK];
  __shared__ __align__(16) short Vt[64 * LDP];
  int b = blockIdx.y;
  int n0 = blockIdx.x * 128;
  int ks = blockIdx.z;
  int tid = threadIdx.x;
  int w = tid >> 6, lane = tid & 63;
  int L = lane & 15, quad = lane >> 4;

  bf16x8 qa[2][2];
#pragma unroll
  for (int qt = 0; qt < 2; ++qt) {
    const short* qb_ = Qg + ((size_t)(b * NPOS + n0 + w * 32 + qt * 16 + L)) * 64;
    qa[qt][0] = *(const bf16x8*)(qb_ + quad * 8);
    qa[qt][1] = *(const bf16x8*)(qb_ + 32 + quad * 8);
  }

  f32x4 o[2][4];
#pragma unroll
  for (int qt = 0; qt < 2; ++qt)
#pragma unroll
    for (int nb = 0; nb < 4; ++nb) o[qt][nb] = (f32x4){0.f, 0.f, 0.f, 0.f};
  float rl[2] = {0.f, 0.f};

  int c8 = tid & 7, dr = tid >> 3;
  i32x4 kr0, kr1, vr0, vr1;
  {
    int kt = ks * TILES_PER_SPLIT;
    const i32x4* src = (const i32x4*)(Kg + ((size_t)(b * NPOS + kt * 64)) * 64);
    kr0 = src[tid]; kr1 = src[tid + 256];
    const short* vbase = Vgt + (size_t)b * NPOS + kt * 64 + c8 * 8;
    vr0 = *(const i32x4*)(vbase + (size_t)dr * NTOT);
    vr1 = *(const i32x4*)(vbase + (size_t)(dr + 32) * NTOT);
  }

  for (int t = 0; t < TILES_PER_SPLIT; ++t) {
    __syncthreads();
    {
      i32x4* dst = (i32x4*)Kt;
      dst[(tid >> 3) * 10 + (tid & 7)] = kr0;
      dst[((tid + 256) >> 3) * 10 + (tid & 7)] = kr1;
      i32x4* vdst = (i32x4*)Vt;
      vdst[dr * 9 + c8] = vr0;
      vdst[(dr + 32) * 9 + c8] = vr1;
    }
    __syncthreads();
    if (t + 1 < TILES_PER_SPLIT) {
      int kt = ks * TILES_PER_SPLIT + t + 1;
      const i32x4* src = (const i32x4*)(Kg + ((size_t)(b * NPOS + kt * 64)) * 64);
      kr0 = src[tid]; kr1 = src[tid + 256];
      const short* vbase = Vgt + (size_t)b * NPOS + kt * 64 + c8 * 8;
      vr0 = *(const i32x4*)(vbase + (size_t)dr * NTOT);
      vr1 = *(const i32x4*)(vbase + (size_t)(dr + 32) * NTOT);
    }

    const i32x4* kt4 = (const i32x4*)Kt;
    // Stage 1: all 16 QK MFMAs (independent)
    f32x4 st[4][2];
#pragma unroll
    for (int kti = 0; kti < 4; ++kti) {
      bf16x8 kf0 = __builtin_bit_cast(bf16x8, kt4[(kti * 16 + L) * 10 + quad]);
      bf16x8 kf1 = __builtin_bit_cast(bf16x8, kt4[(kti * 16 + L) * 10 + 4 + quad]);
#pragma unroll
      for (int qt = 0; qt < 2; ++qt) {
        f32x4 s = {0.f, 0.f, 0.f, 0.f};
        s = __builtin_amdgcn_mfma_f32_16x16x32_bf16(kf0, qa[qt][0], s, 0, 0, 0);
        s = __builtin_amdgcn_mfma_f32_16x16x32_bf16(kf1, qa[qt][1], s, 0, 0, 0);
        st[kti][qt] = s;
      }
    }
    // Stage 2: all 32 exp2 + pack (trans pipe streams)
    bf16x4 pp[4][2];
#pragma unroll
    for (int kti = 0; kti < 4; ++kti)
#pragma unroll
      for (int qt = 0; qt < 2; ++qt) {
        float p0 = __builtin_amdgcn_exp2f(st[kti][qt][0]);
        float p1 = __builtin_amdgcn_exp2f(st[kti][qt][1]);
        float p2 = __builtin_amdgcn_exp2f(st[kti][qt][2]);
        float p3 = __builtin_amdgcn_exp2f(st[kti][qt][3]);
        rl[qt] += (p0 + p1) + (p2 + p3);
        u32 lo = __builtin_amdgcn_perm(__builtin_bit_cast(u32, p1), __builtin_bit_cast(u32, p0), 0x07060302u);
        u32 hi = __builtin_amdgcn_perm(__builtin_bit_cast(u32, p3), __builtin_bit_cast(u32, p2), 0x07060302u);
        u32 pr[2] = {lo, hi};
        pp[kti][qt] = __builtin_bit_cast(bf16x4, pr);
      }
    // Stage 3: all 32 PV MFMAs (8 independent accumulator chains)
#pragma unroll
    for (int nb = 0; nb < 4; ++nb) {
#pragma unroll
      for (int kti = 0; kti < 4; ++kti) {
        bf16x4 va = *(const bf16x4*)(Vt + (nb * 16 + L) * LDP + kti * 16 + quad * 4);
#pragma unroll
        for (int qt = 0; qt < 2; ++qt)
          o[qt][nb] = __builtin_amdgcn_mfma_f32_16x16x16bf16_1k(va, pp[kti][qt], o[qt][nb], 0, 0, 0);
      }
    }
  }

#pragma unroll
  for (int qt = 0; qt < 2; ++qt) {
    rl[qt] += __shfl_xor(rl[qt], 16);
    rl[qt] += __shfl_xor(rl[qt], 32);
  }

#pragma unroll
  for (int qt = 0; qt < 2; ++qt) {
    int qg = b * NPOS + n0 + w * 32 + qt * 16 + L;
#pragma unroll
    for (int nb = 0; nb < 4; ++nb)
#pragma unroll
      for (int ip = 0; ip < 2; ++ip) {
        u32 pk = ((u32)(unsigned short)f2bf(o[qt][nb][2 * ip + 1]) << 16) |
                 (u32)(unsigned short)f2bf(o[qt][nb][2 * ip]);
        int d32 = nb * 8 + quad * 2 + ip;
        PoT[((size_t)(ks * 32 + d32)) * NTOT + qg] = pk;
      }
    if (quad == 0) Pl[(size_t)ks * NTOT + qg] = rl[qt];
  }
}

// ---------------- Kernel C: merge + residual + LN2 + MFMA proj_in (+X2) ----------------
// grid (288) x 256 (exact R13).
__global__ __launch_bounds__(256) void k_res_ln2_proj(
    const float* __restrict__ x, const u32* __restrict__ PoT, const float* __restrict__ Pl,
    const float* __restrict__ ln2w, const float* __restrict__ ln2b,
    const float* __restrict__ piw,
    float* __restrict__ X2, float* __restrict__ Hbuf) {
  __shared__ float s1a[4 * 64], s2a[4 * 64];
  __shared__ __align__(16) short xn[64 * 72];
  int t = threadIdx.x;
  int w = t >> 6;
  int p = t & 63;
  int q0 = blockIdx.x * 64;
  int q = q0 + p;
  int b = q / NPOS;
  int nn = q0 % NPOS;
  int n = q % NPOS;

  float lsum = 0.f;
#pragma unroll
  for (int s = 0; s < NSPLIT; ++s) lsum += Pl[(size_t)s * NTOT + q];
  float inv = 1.f / lsum;

  const float* xb = x + (size_t)b * CH * NPOS + n;
  float xr[16];
  float s1 = 0.f, s2 = 0.f;
#pragma unroll
  for (int j2 = 0; j2 < 8; ++j2) {
    float a0 = 0.f, a1 = 0.f;
#pragma unroll
    for (int s = 0; s < NSPLIT; ++s) {
      u32 v = PoT[((size_t)(s * 32 + w * 8 + j2)) * NTOT + q];
      a0 += __builtin_bit_cast(float, v << 16);
      a1 += __builtin_bit_cast(float, v & 0xffff0000u);
    }
    int cl = 2 * j2;
    int c = w * 16 + cl;
    float v0 = xb[(size_t)c * NPOS] + a0 * inv;
    float v1 = xb[(size_t)(c + 1) * NPOS] + a1 * inv;
    xr[cl] = v0; xr[cl + 1] = v1;
    s1 += v0 + v1;
    s2 += v0 * v0 + v1 * v1;
  }
  s1a[w * 64 + p] = s1;
  s2a[w * 64 + p] = s2;
  {
    float* xo = X2 + (size_t)b * CH * NPOS + n;
#pragma unroll
    for (int cl = 0; cl < 16; ++cl) xo[(size_t)(w * 16 + cl) * NPOS] = xr[cl];
  }
  __syncthreads();
  float mu = 0.f, m2 = 0.f;
#pragma unroll
  for (int ww = 0; ww < 4; ++ww) { mu += s1a[ww * 64 + p]; m2 += s2a[ww * 64 + p]; }
  mu *= (1.f / 64.f);
  float var = m2 * (1.f / 64.f) - mu * mu;
  float rstd = rsqrtf(var + 1e-5f);
  {
    u32* xw = (u32*)xn;
#pragma unroll
    for (int j2 = 0; j2 < 8; ++j2) {
      int cl = 2 * j2, c = w * 16 + cl;
      float y0 = (xr[cl] - mu) * rstd * ln2w[c] + ln2b[c];
      float y1 = (xr[cl + 1] - mu) * rstd * ln2w[c + 1] + ln2b[c + 1];
      u32 pk = ((u32)(unsigned short)f2bf(y1) << 16) | (u32)(unsigned short)f2bf(y0);
      xw[p * 36 + w * 8 + j2] = pk;
    }
  }
  __syncthreads();
  int lane = t & 63;
  int L = lane & 15, quad = lane >> 4;
  bf16x8 a0, a1;
  {
    const float* wr = piw + (w * 16 + L) * 64 + quad * 8;
#pragma unroll
    for (int j = 0; j < 8; ++j) { a0[j] = f2bf(wr[j]); a1[j] = f2bf(wr[32 + j]); }
  }
  float* hb = Hbuf + (size_t)b * CH * NPOS + nn;
#pragma unroll
  for (int pt = 0; pt < 4; ++pt) {
    bf16x8 b0 = *(const bf16x8*)(xn + (pt * 16 + L) * 72 + quad * 8);
    bf16x8 b1 = *(const bf16x8*)(xn + (pt * 16 + L) * 72 + 32 + quad * 8);
    f32x4 acc = {0.f, 0.f, 0.f, 0.f};
    acc = __builtin_amdgcn_mfma_f32_16x16x32_bf16(a0, b0, acc, 0, 0, 0);
    acc = __builtin_amdgcn_mfma_f32_16x16x32_bf16(a1, b1, acc, 0, 0, 0);
#pragma unroll
    for (int i = 0; i < 4; ++i)
      hb[(size_t)(w * 16 + quad * 4 + i) * NPOS + pt * 16 + L] = acc[i];
  }
}

// ---------------- Kernel D: per-patch spectral filter ----------------
// grid (288) x 64.
__global__ __launch_bounds__(64) void k_fft(float* __restrict__ Hbuf, const float* __restrict__ fftw) {
  int idx = blockIdx.x * 64 + threadIdx.x;
  int wb = idx % 12;
  int t = idx / 12;
  int hb = t % 12;
  int t2 = t / 12;
  int c = t2 % 64;
  int b = t2 / 64;
  float* base = Hbuf + (size_t)(b * CH + c) * NPOS + (hb * 8) * 96 + wb * 8;
  const float r = 0.70710678118654752440f;
  const float CO[8] = {1.f, r, 0.f, -r, -1.f, -r, 0.f, r};
  const float SI[8] = {0.f, r, 1.f, r, 0.f, -r, -1.f, -r};
  float Ar[8][5], Ai[8][5];
#pragma unroll
  for (int p = 0; p < 8; ++p) {
    f32x4 ra = *(const f32x4*)(base + p * 96);
    f32x4 rb = *(const f32x4*)(base + p * 96 + 4);
    float row[8] = {ra[0], ra[1], ra[2], ra[3], rb[0], rb[1], rb[2], rb[3]};
#pragma unroll
    for (int v = 0; v < 5; ++v) {
      float sr = 0.f, si = 0.f;
#pragma unroll
      for (int q = 0; q < 8; ++q) {
        int k = (q * v) & 7;
        sr += row[q] * CO[k];
        si -= row[q] * SI[k];
      }
      Ar[p][v] = sr;
      Ai[p][v] = si;
    }
  }
  const float* wp = fftw + c * 40;
#pragma unroll
  for (int v = 0; v < 5; ++v) {
    float Br[8], Bi[8];
#pragma unroll
    for (int u = 0; u < 8; ++u) {
      float cr = 0.f, ci = 0.f;
#pragma unroll
      for (int p = 0; p < 8; ++p) {
        int k = (p * u) & 7;
        float cc = CO[k], ss = SI[k];
        cr += Ar[p][v] * cc + Ai[p][v] * ss;
        ci += Ai[p][v] * cc - Ar[p][v] * ss;
      }
      float wv = wp[u * 5 + v];
      Br[u] = cr * wv;
      Bi[u] = ci * wv;
    }
#pragma unroll
    for (int p = 0; p < 8; ++p) {
      float yr = 0.f, yi = 0.f;
#pragma unroll
      for (int u = 0; u < 8; ++u) {
        int k = (p * u) & 7;
        float cc = CO[k], ss = SI[k];
        yr += Br[u] * cc - Bi[u] * ss;
        yi += Bi[u] * cc + Br[u] * ss;
      }
      Ar[p][v] = yr * 0.125f;
      Ai[p][v] = yi * 0.125f;
    }
  }
#pragma unroll
  for (int p = 0; p < 8; ++p) {
    float outv[8];
#pragma unroll
    for (int q = 0; q < 8; ++q) {
      float acc = Ar[p][0] + ((q & 1) ? -Ar[p][4] : Ar[p][4]);
#pragma unroll
      for (int v = 1; v < 4; ++v) {
        int k = (q * v) & 7;
        acc += 2.f * (Ar[p][v] * CO[k] - Ai[p][v] * SI[k]);
      }
      outv[q] = acc * 0.125f;
    }
    f32x4 wa = {outv[0], outv[1], outv[2], outv[3]};
    f32x4 wb2 = {outv[4], outv[5], outv[6], outv[7]};
    *(f32x4*)(base + p * 96) = wa;
    *(f32x4*)(base + p * 96 + 4) = wb2;
  }
}

// ---------------- Kernel E1: dwconv3x3 + gelu-gate -> G ----------------
// grid (72, 32) x 256.
__global__ __launch_bounds__(256) void k_dw_gate(
    const float* __restrict__ Hbuf, const float* __restrict__ dww,
    float* __restrict__ G) {
  int cc = blockIdx.y;
  int q = blockIdx.x * 256 + threadIdx.x;
  int b = q / NPOS, n = q % NPOS;
  int y = n / 96, xx = n % 96;
  const float* h1 = Hbuf + (size_t)(b * CH + cc) * NPOS;
  const float* h2 = Hbuf + (size_t)(b * CH + cc + 32) * NPOS;
  float wd1[9], wd2[9];
#pragma unroll
  for (int ki = 0; ki < 9; ++ki) { wd1[ki] = dww[cc * 9 + ki]; wd2[ki] = dww[(cc + 32) * 9 + ki]; }
  float d1 = 0.f, d2 = 0.f;
  for (int dy = -1; dy <= 1; ++dy) {
    int yy = y + dy;
    if (yy < 0 || yy >= 96) continue;
    for (int dx = -1; dx <= 1; ++dx) {
      int xv = xx + dx;
      if (xv < 0 || xv >= 96) continue;
      int ki = (dy + 1) * 3 + (dx + 1);
      d1 += h1[yy * 96 + xv] * wd1[ki];
      d2 += h2[yy * 96 + xv] * wd2[ki];
    }
  }
  G[(size_t)cc * NTOT + q] = gelu_exact(d1) * d2;
}

// ---------------- Kernel E2: proj_out + residual ----------------
// grid (72, 8) x 256 (exact R13; G is L2-resident so 8x re-read is cheap).
__global__ __launch_bounds__(256) void k_proj_out(
    const float* __restrict__ G, const float* __restrict__ poww,
    const float* __restrict__ X2, float* __restrict__ out) {
  int og = blockIdx.y;
  int q = blockIdx.x * 256 + threadIdx.x;
  int b = q / NPOS, n = q % NPOS;
  float g[32];
#pragma unroll
  for (int cg = 0; cg < 32; ++cg) g[cg] = G[(size_t)cg * NTOT + q];
  const float* xr = X2 + (size_t)b * CH * NPOS + n;
  float* ob = out + (size_t)b * CH * NPOS + n;
#pragma unroll
  for (int j = 0; j < 8; ++j) {
    int oc = og * 8 + j;
    const float* prow = poww + oc * 32;
    float acc = xr[(size_t)oc * NPOS];
#pragma unroll
    for (int cg = 0; cg < 32; ++cg) acc += prow[cg] * g[cg];
    ob[(size_t)oc * NPOS] = acc;
  }
}

extern "C" void kernel_launch(void* const* d_in, const int* in_sizes, int n_in,
                              void* d_out, int out_size, void* d_ws, size_t ws_size,
                              hipStream_t stream) {
  const float* x    = (const float*)d_in[0];
  const float* ln1w = (const float*)d_in[1];
  const float* ln1b = (const float*)d_in[2];
  const float* ln2w = (const float*)d_in[3];
  const float* ln2b = (const float*)d_in[4];
  const float* qw   = (const float*)d_in[5];
  const float* qb   = (const float*)d_in[6];
  const float* kw   = (const float*)d_in[7];
  const float* kb   = (const float*)d_in[8];
  const float* vw   = (const float*)d_in[9];
  const float* vb   = (const float*)d_in[10];
  const float* fftw = (const float*)d_in[11];
  const float* piw  = (const float*)d_in[12];
  const float* dww  = (const float*)d_in[13];
  const float* poww = (const float*)d_in[14];

  short* Qg  = (short*)d_ws;
  short* Kg  = Qg + (size_t)NTOT * 64;
  short* Vgt = Kg + (size_t)NTOT * 64;
  u32*   PoT = (u32*)(Vgt + (size_t)NTOT * 64);
  float* Pl  = (float*)(PoT + (size_t)NSPLIT * 32 * NTOT);
  float* X2  = Pl + (size_t)NSPLIT * NTOT;
  float* Hbuf = X2 + (size_t)NTOT * 64;
  float* G   = Hbuf + (size_t)NTOT * 64;

  k_ln_qkv<<<dim3(72, 3, 2), 256, 0, stream>>>(x, ln1w, ln1b, qw, qb, kw, kb, vw, vb, Qg, Kg, Vgt);
  k_attn<<<dim3(72, 2, NSPLIT), 256, 0, stream>>>(Qg, Kg, Vgt, PoT, Pl);
  k_res_ln2_proj<<<dim3(288), 256, 0, stream>>>(x, PoT, Pl, ln2w, ln2b, piw, X2, Hbuf);
  k_fft<<<dim3(288), 64, 0, stream>>>(Hbuf, fftw);
  k_dw_gate<<<dim3(72, 32), 256, 0, stream>>>(Hbuf, dww, G);
  k_proj_out<<<dim3(72, 8), 256, 0, stream>>>(G, poww, X2, (float*)d_out);
}

// Round 17
// 209.935 us; speedup vs baseline: 1.0605x; 1.0270x over previous
//
#include <hip/hip_runtime.h>
#include <hip/hip_bf16.h>
#include <math.h>

#define CH 64
#define NPOS 9216   // 96*96
#define NTOT 18432  // 2*9216
#define NSPLIT 8
#define TILES_PER_SPLIT 18   // 144/8
#define LOG2E 1.4426950408889634f

typedef short bf16x8 __attribute__((ext_vector_type(8)));
typedef short bf16x4 __attribute__((ext_vector_type(4)));
typedef float f32x4 __attribute__((ext_vector_type(4)));
typedef int   i32x4 __attribute__((ext_vector_type(4)));
typedef unsigned int u32;

__device__ __forceinline__ float bf2f(short s) {
  unsigned int u = ((unsigned int)(unsigned short)s) << 16;
  return __builtin_bit_cast(float, u);
}
__device__ __forceinline__ short f2bf(float f) {
  unsigned int u = __builtin_bit_cast(unsigned int, f);
  unsigned int r = (u + 0x7fffu + ((u >> 16) & 1u)) >> 16;  // RNE
  return (short)r;
}
__device__ __forceinline__ float gelu_exact(float x) {
  return 0.5f * x * (1.f + erff(x * 0.70710678118654752440f));
}

// R16: stage-batching regressed (VGPR 88, Occ 17%). R17: all kernels exact R13;
// attn re-blocked 256->128 threads (64q/block, 2 waves, same 32q/wave shape):
// grid 2304 blocks -> LDS-capped 8 blocks/CU = 16 waves/CU (~2.2x measured 7.3).

// ---------------- Kernel A: LN1 + QKV projection ----------------
// grid (72, 3, 2) x 256. Q/K -> [n][c]; V -> TRANSPOSED [c][n].
__global__ __launch_bounds__(256) void k_ln_qkv(
    const float* __restrict__ x, const float* __restrict__ ln1w, const float* __restrict__ ln1b,
    const float* __restrict__ qw, const float* __restrict__ qb,
    const float* __restrict__ kw, const float* __restrict__ kb,
    const float* __restrict__ vw, const float* __restrict__ vb,
    short* __restrict__ Qg, short* __restrict__ Kg, short* __restrict__ Vgt) {
  int mat = blockIdx.y;
  int half = blockIdx.z;
  const float* wsrc = (mat == 0) ? qw : (mat == 1) ? kw : vw;
  const float* bsrc = (mat == 0) ? qb : (mat == 1) ? kb : vb;
  int idx = blockIdx.x * 256 + threadIdx.x;
  int b = idx / NPOS, n = idx % NPOS;
  const float* xb = x + (size_t)b * CH * NPOS + n;
  float xr[64];
  float mu = 0.f;
#pragma unroll
  for (int c = 0; c < 64; ++c) { float v = xb[c * NPOS]; xr[c] = v; mu += v; }
  mu *= (1.f / 64.f);
  float var = 0.f;
#pragma unroll
  for (int c = 0; c < 64; ++c) { float d = xr[c] - mu; var += d * d; }
  float rstd = rsqrtf(var * (1.f / 64.f) + 1e-5f);
#pragma unroll
  for (int c = 0; c < 64; ++c) xr[c] = (xr[c] - mu) * rstd * ln1w[c] + ln1b[c];
  if (mat == 2) {
    for (int o2 = 0; o2 < 4; ++o2) {
#pragma unroll
      for (int j = 0; j < 8; ++j) {
        int o = half * 32 + o2 * 8 + j;
        float acc = bsrc[o];
        const float* wrow = wsrc + o * 64;
#pragma unroll
        for (int c = 0; c < 64; ++c) acc += wrow[c] * xr[c];
        Vgt[(size_t)o * NTOT + idx] = f2bf(acc);
      }
    }
  } else {
    float kscale = (mat == 1) ? LOG2E : 1.f;
    short* outp = ((mat == 0) ? Qg : Kg) + (size_t)idx * 64 + half * 32;
    for (int o2 = 0; o2 < 4; ++o2) {
      bf16x8 v8;
#pragma unroll
      for (int j = 0; j < 8; ++j) {
        int o = half * 32 + o2 * 8 + j;
        float acc = bsrc[o];
        const float* wrow = wsrc + o * 64;
#pragma unroll
        for (int c = 0; c < 64; ++c) acc += wrow[c] * xr[c];
        v8[j] = f2bf(acc * kscale);
      }
      *(bf16x8*)(outp + o2 * 8) = v8;
    }
  }
}

// ---------------- Kernel B: MFMA flash attention (R13 math, 128-thr blocks) ----------------
// grid (144, 2, NSPLIT) x 128. 64 q/block, 32 q/wave (2 waves).
#define LDPK 80
#define LDP  72
__global__ __launch_bounds__(128) void k_attn(
    const short* __restrict__ Qg, const short* __restrict__ Kg, const short* __restrict__ Vgt,
    u32* __restrict__ PoT, float* __restrict__ Pl) {
  __shared__ __align__(16) short Kt[64 * LDPK];
  __shared__ __align__(16) short Vt[64 * LDP];
  int b = blockIdx.y;
  int n0 = blockIdx.x * 64;
  int ks = blockIdx.z;
  int tid = threadIdx.x;
  int w = tid >> 6, lane = tid & 63;
  int L = lane & 15, quad = lane >> 4;

  bf16x8 qa[2][2];
#pragma unroll
  for (int qt = 0; qt < 2; ++qt) {
    const short* qb_ = Qg + ((size_t)(b * NPOS + n0 + w * 32 + qt * 16 + L)) * 64;
    qa[qt][0] = *(const bf16x8*)(qb_ + quad * 8);
    qa[qt][1] = *(const bf16x8*)(qb_ + 32 + quad * 8);
  }

  f32x4 o[2][4];
#pragma unroll
  for (int qt = 0; qt < 2; ++qt)
#pragma unroll
    for (int nb = 0; nb < 4; ++nb) o[qt][nb] = (f32x4){0.f, 0.f, 0.f, 0.f};
  float rl[2] = {0.f, 0.f};

  int c8 = tid & 7, dr = tid >> 3;   // dr in 0..15
  i32x4 kr[4], vr[4];
  {
    int kt = ks * TILES_PER_SPLIT;
    const i32x4* src = (const i32x4*)(Kg + ((size_t)(b * NPOS + kt * 64)) * 64);
#pragma unroll
    for (int it = 0; it < 4; ++it) kr[it] = src[tid + it * 128];
    const short* vbase = Vgt + (size_t)b * NPOS + kt * 64 + c8 * 8;
#pragma unroll
    for (int it = 0; it < 4; ++it)
      vr[it] = *(const i32x4*)(vbase + (size_t)(dr + it * 16) * NTOT);
  }

  for (int t = 0; t < TILES_PER_SPLIT; ++t) {
    __syncthreads();
    {
      i32x4* dst = (i32x4*)Kt;
#pragma unroll
      for (int it = 0; it < 4; ++it) {
        int e = tid + it * 128;
        dst[(e >> 3) * 10 + (e & 7)] = kr[it];
      }
      i32x4* vdst = (i32x4*)Vt;
#pragma unroll
      for (int it = 0; it < 4; ++it)
        vdst[(dr + it * 16) * 9 + c8] = vr[it];
    }
    __syncthreads();
    if (t + 1 < TILES_PER_SPLIT) {
      int kt = ks * TILES_PER_SPLIT + t + 1;
      const i32x4* src = (const i32x4*)(Kg + ((size_t)(b * NPOS + kt * 64)) * 64);
#pragma unroll
      for (int it = 0; it < 4; ++it) kr[it] = src[tid + it * 128];
      const short* vbase = Vgt + (size_t)b * NPOS + kt * 64 + c8 * 8;
#pragma unroll
      for (int it = 0; it < 4; ++it)
        vr[it] = *(const i32x4*)(vbase + (size_t)(dr + it * 16) * NTOT);
    }

    const i32x4* kt4 = (const i32x4*)Kt;
#pragma unroll
    for (int kti = 0; kti < 4; ++kti) {
      bf16x8 kf0 = __builtin_bit_cast(bf16x8, kt4[(kti * 16 + L) * 10 + quad]);
      bf16x8 kf1 = __builtin_bit_cast(bf16x8, kt4[(kti * 16 + L) * 10 + 4 + quad]);
      bf16x4 pp[2];
#pragma unroll
      for (int qt = 0; qt < 2; ++qt) {
        f32x4 st = {0.f, 0.f, 0.f, 0.f};
        st = __builtin_amdgcn_mfma_f32_16x16x32_bf16(kf0, qa[qt][0], st, 0, 0, 0);
        st = __builtin_amdgcn_mfma_f32_16x16x32_bf16(kf1, qa[qt][1], st, 0, 0, 0);
        float p0 = __builtin_amdgcn_exp2f(st[0]);
        float p1 = __builtin_amdgcn_exp2f(st[1]);
        float p2 = __builtin_amdgcn_exp2f(st[2]);
        float p3 = __builtin_amdgcn_exp2f(st[3]);
        rl[qt] += (p0 + p1) + (p2 + p3);
        u32 lo = __builtin_amdgcn_perm(__builtin_bit_cast(u32, p1), __builtin_bit_cast(u32, p0), 0x07060302u);
        u32 hi = __builtin_amdgcn_perm(__builtin_bit_cast(u32, p3), __builtin_bit_cast(u32, p2), 0x07060302u);
        u32 pr[2] = {lo, hi};
        pp[qt] = __builtin_bit_cast(bf16x4, pr);
      }
#pragma unroll
      for (int nb = 0; nb < 4; ++nb) {
        bf16x4 va = *(const bf16x4*)(Vt + (nb * 16 + L) * LDP + kti * 16 + quad * 4);
#pragma unroll
        for (int qt = 0; qt < 2; ++qt)
          o[qt][nb] = __builtin_amdgcn_mfma_f32_16x16x16bf16_1k(va, pp[qt], o[qt][nb], 0, 0, 0);
      }
    }
  }

#pragma unroll
  for (int qt = 0; qt < 2; ++qt) {
    rl[qt] += __shfl_xor(rl[qt], 16);
    rl[qt] += __shfl_xor(rl[qt], 32);
  }

#pragma unroll
  for (int qt = 0; qt < 2; ++qt) {
    int qg = b * NPOS + n0 + w * 32 + qt * 16 + L;
#pragma unroll
    for (int nb = 0; nb < 4; ++nb)
#pragma unroll
      for (int ip = 0; ip < 2; ++ip) {
        u32 pk = ((u32)(unsigned short)f2bf(o[qt][nb][2 * ip + 1]) << 16) |
                 (u32)(unsigned short)f2bf(o[qt][nb][2 * ip]);
        int d32 = nb * 8 + quad * 2 + ip;
        PoT[((size_t)(ks * 32 + d32)) * NTOT + qg] = pk;
      }
    if (quad == 0) Pl[(size_t)ks * NTOT + qg] = rl[qt];
  }
}

// ---------------- Kernel C: merge + residual + LN2 + MFMA proj_in (+X2) ----------------
// grid (288) x 256 (exact R13).
__global__ __launch_bounds__(256) void k_res_ln2_proj(
    const float* __restrict__ x, const u32* __restrict__ PoT, const float* __restrict__ Pl,
    const float* __restrict__ ln2w, const float* __restrict__ ln2b,
    const float* __restrict__ piw,
    float* __restrict__ X2, float* __restrict__ Hbuf) {
  __shared__ float s1a[4 * 64], s2a[4 * 64];
  __shared__ __align__(16) short xn[64 * 72];
  int t = threadIdx.x;
  int w = t >> 6;
  int p = t & 63;
  int q0 = blockIdx.x * 64;
  int q = q0 + p;
  int b = q / NPOS;
  int nn = q0 % NPOS;
  int n = q % NPOS;

  float lsum = 0.f;
#pragma unroll
  for (int s = 0; s < NSPLIT; ++s) lsum += Pl[(size_t)s * NTOT + q];
  float inv = 1.f / lsum;

  const float* xb = x + (size_t)b * CH * NPOS + n;
  float xr[16];
  float s1 = 0.f, s2 = 0.f;
#pragma unroll
  for (int j2 = 0; j2 < 8; ++j2) {
    float a0 = 0.f, a1 = 0.f;
#pragma unroll
    for (int s = 0; s < NSPLIT; ++s) {
      u32 v = PoT[((size_t)(s * 32 + w * 8 + j2)) * NTOT + q];
      a0 += __builtin_bit_cast(float, v << 16);
      a1 += __builtin_bit_cast(float, v & 0xffff0000u);
    }
    int cl = 2 * j2;
    int c = w * 16 + cl;
    float v0 = xb[(size_t)c * NPOS] + a0 * inv;
    float v1 = xb[(size_t)(c + 1) * NPOS] + a1 * inv;
    xr[cl] = v0; xr[cl + 1] = v1;
    s1 += v0 + v1;
    s2 += v0 * v0 + v1 * v1;
  }
  s1a[w * 64 + p] = s1;
  s2a[w * 64 + p] = s2;
  {
    float* xo = X2 + (size_t)b * CH * NPOS + n;
#pragma unroll
    for (int cl = 0; cl < 16; ++cl) xo[(size_t)(w * 16 + cl) * NPOS] = xr[cl];
  }
  __syncthreads();
  float mu = 0.f, m2 = 0.f;
#pragma unroll
  for (int ww = 0; ww < 4; ++ww) { mu += s1a[ww * 64 + p]; m2 += s2a[ww * 64 + p]; }
  mu *= (1.f / 64.f);
  float var = m2 * (1.f / 64.f) - mu * mu;
  float rstd = rsqrtf(var + 1e-5f);
  {
    u32* xw = (u32*)xn;
#pragma unroll
    for (int j2 = 0; j2 < 8; ++j2) {
      int cl = 2 * j2, c = w * 16 + cl;
      float y0 = (xr[cl] - mu) * rstd * ln2w[c] + ln2b[c];
      float y1 = (xr[cl + 1] - mu) * rstd * ln2w[c + 1] + ln2b[c + 1];
      u32 pk = ((u32)(unsigned short)f2bf(y1) << 16) | (u32)(unsigned short)f2bf(y0);
      xw[p * 36 + w * 8 + j2] = pk;
    }
  }
  __syncthreads();
  int lane = t & 63;
  int L = lane & 15, quad = lane >> 4;
  bf16x8 a0, a1;
  {
    const float* wr = piw + (w * 16 + L) * 64 + quad * 8;
#pragma unroll
    for (int j = 0; j < 8; ++j) { a0[j] = f2bf(wr[j]); a1[j] = f2bf(wr[32 + j]); }
  }
  float* hb = Hbuf + (size_t)b * CH * NPOS + nn;
#pragma unroll
  for (int pt = 0; pt < 4; ++pt) {
    bf16x8 b0 = *(const bf16x8*)(xn + (pt * 16 + L) * 72 + quad * 8);
    bf16x8 b1 = *(const bf16x8*)(xn + (pt * 16 + L) * 72 + 32 + quad * 8);
    f32x4 acc = {0.f, 0.f, 0.f, 0.f};
    acc = __builtin_amdgcn_mfma_f32_16x16x32_bf16(a0, b0, acc, 0, 0, 0);
    acc = __builtin_amdgcn_mfma_f32_16x16x32_bf16(a1, b1, acc, 0, 0, 0);
#pragma unroll
    for (int i = 0; i < 4; ++i)
      hb[(size_t)(w * 16 + quad * 4 + i) * NPOS + pt * 16 + L] = acc[i];
  }
}

// ---------------- Kernel D: per-patch spectral filter ----------------
// grid (288) x 64.
__global__ __launch_bounds__(64) void k_fft(float* __restrict__ Hbuf, const float* __restrict__ fftw) {
  int idx = blockIdx.x * 64 + threadIdx.x;
  int wb = idx % 12;
  int t = idx / 12;
  int hb = t % 12;
  int t2 = t / 12;
  int c = t2 % 64;
  int b = t2 / 64;
  float* base = Hbuf + (size_t)(b * CH + c) * NPOS + (hb * 8) * 96 + wb * 8;
  const float r = 0.70710678118654752440f;
  const float CO[8] = {1.f, r, 0.f, -r, -1.f, -r, 0.f, r};
  const float SI[8] = {0.f, r, 1.f, r, 0.f, -r, -1.f, -r};
  float Ar[8][5], Ai[8][5];
#pragma unroll
  for (int p = 0; p < 8; ++p) {
    f32x4 ra = *(const f32x4*)(base + p * 96);
    f32x4 rb = *(const f32x4*)(base + p * 96 + 4);
    float row[8] = {ra[0], ra[1], ra[2], ra[3], rb[0], rb[1], rb[2], rb[3]};
#pragma unroll
    for (int v = 0; v < 5; ++v) {
      float sr = 0.f, si = 0.f;
#pragma unroll
      for (int q = 0; q < 8; ++q) {
        int k = (q * v) & 7;
        sr += row[q] * CO[k];
        si -= row[q] * SI[k];
      }
      Ar[p][v] = sr;
      Ai[p][v] = si;
    }
  }
  const float* wp = fftw + c * 40;
#pragma unroll
  for (int v = 0; v < 5; ++v) {
    float Br[8], Bi[8];
#pragma unroll
    for (int u = 0; u < 8; ++u) {
      float cr = 0.f, ci = 0.f;
#pragma unroll
      for (int p = 0; p < 8; ++p) {
        int k = (p * u) & 7;
        float cc = CO[k], ss = SI[k];
        cr += Ar[p][v] * cc + Ai[p][v] * ss;
        ci += Ai[p][v] * cc - Ar[p][v] * ss;
      }
      float wv = wp[u * 5 + v];
      Br[u] = cr * wv;
      Bi[u] = ci * wv;
    }
#pragma unroll
    for (int p = 0; p < 8; ++p) {
      float yr = 0.f, yi = 0.f;
#pragma unroll
      for (int u = 0; u < 8; ++u) {
        int k = (p * u) & 7;
        float cc = CO[k], ss = SI[k];
        yr += Br[u] * cc - Bi[u] * ss;
        yi += Bi[u] * cc + Br[u] * ss;
      }
      Ar[p][v] = yr * 0.125f;
      Ai[p][v] = yi * 0.125f;
    }
  }
#pragma unroll
  for (int p = 0; p < 8; ++p) {
    float outv[8];
#pragma unroll
    for (int q = 0; q < 8; ++q) {
      float acc = Ar[p][0] + ((q & 1) ? -Ar[p][4] : Ar[p][4]);
#pragma unroll
      for (int v = 1; v < 4; ++v) {
        int k = (q * v) & 7;
        acc += 2.f * (Ar[p][v] * CO[k] - Ai[p][v] * SI[k]);
      }
      outv[q] = acc * 0.125f;
    }
    f32x4 wa = {outv[0], outv[1], outv[2], outv[3]};
    f32x4 wb2 = {outv[4], outv[5], outv[6], outv[7]};
    *(f32x4*)(base + p * 96) = wa;
    *(f32x4*)(base + p * 96 + 4) = wb2;
  }
}

// ---------------- Kernel E1: dwconv3x3 + gelu-gate -> G ----------------
// grid (72, 32) x 256.
__global__ __launch_bounds__(256) void k_dw_gate(
    const float* __restrict__ Hbuf, const float* __restrict__ dww,
    float* __restrict__ G) {
  int cc = blockIdx.y;
  int q = blockIdx.x * 256 + threadIdx.x;
  int b = q / NPOS, n = q % NPOS;
  int y = n / 96, xx = n % 96;
  const float* h1 = Hbuf + (size_t)(b * CH + cc) * NPOS;
  const float* h2 = Hbuf + (size_t)(b * CH + cc + 32) * NPOS;
  float wd1[9], wd2[9];
#pragma unroll
  for (int ki = 0; ki < 9; ++ki) { wd1[ki] = dww[cc * 9 + ki]; wd2[ki] = dww[(cc + 32) * 9 + ki]; }
  float d1 = 0.f, d2 = 0.f;
  for (int dy = -1; dy <= 1; ++dy) {
    int yy = y + dy;
    if (yy < 0 || yy >= 96) continue;
    for (int dx = -1; dx <= 1; ++dx) {
      int xv = xx + dx;
      if (xv < 0 || xv >= 96) continue;
      int ki = (dy + 1) * 3 + (dx + 1);
      d1 += h1[yy * 96 + xv] * wd1[ki];
      d2 += h2[yy * 96 + xv] * wd2[ki];
    }
  }
  G[(size_t)cc * NTOT + q] = gelu_exact(d1) * d2;
}

// ---------------- Kernel E2: proj_out + residual ----------------
// grid (72, 8) x 256 (exact R13).
__global__ __launch_bounds__(256) void k_proj_out(
    const float* __restrict__ G, const float* __restrict__ poww,
    const float* __restrict__ X2, float* __restrict__ out) {
  int og = blockIdx.y;
  int q = blockIdx.x * 256 + threadIdx.x;
  int b = q / NPOS, n = q % NPOS;
  float g[32];
#pragma unroll
  for (int cg = 0; cg < 32; ++cg) g[cg] = G[(size_t)cg * NTOT + q];
  const float* xr = X2 + (size_t)b * CH * NPOS + n;
  float* ob = out + (size_t)b * CH * NPOS + n;
#pragma unroll
  for (int j = 0; j < 8; ++j) {
    int oc = og * 8 + j;
    const float* prow = poww + oc * 32;
    float acc = xr[(size_t)oc * NPOS];
#pragma unroll
    for (int cg = 0; cg < 32; ++cg) acc += prow[cg] * g[cg];
    ob[(size_t)oc * NPOS] = acc;
  }
}

extern "C" void kernel_launch(void* const* d_in, const int* in_sizes, int n_in,
                              void* d_out, int out_size, void* d_ws, size_t ws_size,
                              hipStream_t stream) {
  const float* x    = (const float*)d_in[0];
  const float* ln1w = (const float*)d_in[1];
  const float* ln1b = (const float*)d_in[2];
  const float* ln2w = (const float*)d_in[3];
  const float* ln2b = (const float*)d_in[4];
  const float* qw   = (const float*)d_in[5];
  const float* qb   = (const float*)d_in[6];
  const float* kw   = (const float*)d_in[7];
  const float* kb   = (const float*)d_in[8];
  const float* vw   = (const float*)d_in[9];
  const float* vb   = (const float*)d_in[10];
  const float* fftw = (const float*)d_in[11];
  const float* piw  = (const float*)d_in[12];
  const float* dww  = (const float*)d_in[13];
  const float* poww = (const float*)d_in[14];

  short* Qg  = (short*)d_ws;
  short* Kg  = Qg + (size_t)NTOT * 64;
  short* Vgt = Kg + (size_t)NTOT * 64;
  u32*   PoT = (u32*)(Vgt + (size_t)NTOT * 64);
  float* Pl  = (float*)(PoT + (size_t)NSPLIT * 32 * NTOT);
  float* X2  = Pl + (size_t)NSPLIT * NTOT;
  float* Hbuf = X2 + (size_t)NTOT * 64;
  float* G   = Hbuf + (size_t)NTOT * 64;

  k_ln_qkv<<<dim3(72, 3, 2), 256, 0, stream>>>(x, ln1w, ln1b, qw, qb, kw, kb, vw, vb, Qg, Kg, Vgt);
  k_attn<<<dim3(144, 2, NSPLIT), 128, 0, stream>>>(Qg, Kg, Vgt, PoT, Pl);
  k_res_ln2_proj<<<dim3(288), 256, 0, stream>>>(x, PoT, Pl, ln2w, ln2b, piw, X2, Hbuf);
  k_fft<<<dim3(288), 64, 0, stream>>>(Hbuf, fftw);
  k_dw_gate<<<dim3(72, 32), 256, 0, stream>>>(Hbuf, dww, G);
  k_proj_out<<<dim3(72, 8), 256, 0, stream>>>(G, poww, X2, (float*)d_out);
}

// Round 18
// 205.965 us; speedup vs baseline: 1.0809x; 1.0193x over previous
//
#include <hip/hip_runtime.h>
#include <hip/hip_bf16.h>
#include <math.h>

#define CH 64
#define NPOS 9216   // 96*96
#define NTOT 18432  // 2*9216
#define NSPLIT 8
#define TILES_PER_SPLIT 18   // 144/8
#define LOG2E 1.4426950408889634f

typedef short bf16x8 __attribute__((ext_vector_type(8)));
typedef short bf16x4 __attribute__((ext_vector_type(4)));
typedef float f32x4 __attribute__((ext_vector_type(4)));
typedef int   i32x4 __attribute__((ext_vector_type(4)));
typedef unsigned int u32;

__device__ __forceinline__ float bf2f(short s) {
  unsigned int u = ((unsigned int)(unsigned short)s) << 16;
  return __builtin_bit_cast(float, u);
}
__device__ __forceinline__ short f2bf(float f) {
  unsigned int u = __builtin_bit_cast(unsigned int, f);
  unsigned int r = (u + 0x7fffu + ((u >> 16) & 1u)) >> 16;  // RNE
  return (short)r;
}
__device__ __forceinline__ float gelu_exact(float x) {
  return 0.5f * x * (1.f + erff(x * 0.70710678118654752440f));
}

// R17: re-blocking neutral — attn is barrier-serialized (2 barriers x 18 iters,
// ~70% stall). R18: exact R13 + double-buffered K/V LDS -> ONE barrier/iter;
// next-tile global loads issued before the barrier, LDS writes into the other
// buffer after compute. Same math, bit-identical result.

// ---------------- Kernel A: LN1 + QKV projection ----------------
// grid (72, 3, 2) x 256. Q/K -> [n][c]; V -> TRANSPOSED [c][n].
__global__ __launch_bounds__(256) void k_ln_qkv(
    const float* __restrict__ x, const float* __restrict__ ln1w, const float* __restrict__ ln1b,
    const float* __restrict__ qw, const float* __restrict__ qb,
    const float* __restrict__ kw, const float* __restrict__ kb,
    const float* __restrict__ vw, const float* __restrict__ vb,
    short* __restrict__ Qg, short* __restrict__ Kg, short* __restrict__ Vgt) {
  int mat = blockIdx.y;
  int half = blockIdx.z;
  const float* wsrc = (mat == 0) ? qw : (mat == 1) ? kw : vw;
  const float* bsrc = (mat == 0) ? qb : (mat == 1) ? kb : vb;
  int idx = blockIdx.x * 256 + threadIdx.x;
  int b = idx / NPOS, n = idx % NPOS;
  const float* xb = x + (size_t)b * CH * NPOS + n;
  float xr[64];
  float mu = 0.f;
#pragma unroll
  for (int c = 0; c < 64; ++c) { float v = xb[c * NPOS]; xr[c] = v; mu += v; }
  mu *= (1.f / 64.f);
  float var = 0.f;
#pragma unroll
  for (int c = 0; c < 64; ++c) { float d = xr[c] - mu; var += d * d; }
  float rstd = rsqrtf(var * (1.f / 64.f) + 1e-5f);
#pragma unroll
  for (int c = 0; c < 64; ++c) xr[c] = (xr[c] - mu) * rstd * ln1w[c] + ln1b[c];
  if (mat == 2) {
    for (int o2 = 0; o2 < 4; ++o2) {
#pragma unroll
      for (int j = 0; j < 8; ++j) {
        int o = half * 32 + o2 * 8 + j;
        float acc = bsrc[o];
        const float* wrow = wsrc + o * 64;
#pragma unroll
        for (int c = 0; c < 64; ++c) acc += wrow[c] * xr[c];
        Vgt[(size_t)o * NTOT + idx] = f2bf(acc);
      }
    }
  } else {
    float kscale = (mat == 1) ? LOG2E : 1.f;
    short* outp = ((mat == 0) ? Qg : Kg) + (size_t)idx * 64 + half * 32;
    for (int o2 = 0; o2 < 4; ++o2) {
      bf16x8 v8;
#pragma unroll
      for (int j = 0; j < 8; ++j) {
        int o = half * 32 + o2 * 8 + j;
        float acc = bsrc[o];
        const float* wrow = wsrc + o * 64;
#pragma unroll
        for (int c = 0; c < 64; ++c) acc += wrow[c] * xr[c];
        v8[j] = f2bf(acc * kscale);
      }
      *(bf16x8*)(outp + o2 * 8) = v8;
    }
  }
}

// ---------------- Kernel B: MFMA flash attention (R13 + LDS double-buffer) ----------------
// grid (72, 2, NSPLIT) x 256. 128 q/block, 32 q/wave. ONE barrier per K-tile.
#define LDPK 80
#define LDP  72
__global__ __launch_bounds__(256) void k_attn(
    const short* __restrict__ Qg, const short* __restrict__ Kg, const short* __restrict__ Vgt,
    u32* __restrict__ PoT, float* __restrict__ Pl) {
  __shared__ __align__(16) short Kt[2][64 * LDPK];
  __shared__ __align__(16) short Vt[2][64 * LDP];
  int b = blockIdx.y;
  int n0 = blockIdx.x * 128;
  int ks = blockIdx.z;
  int tid = threadIdx.x;
  int w = tid >> 6, lane = tid & 63;
  int L = lane & 15, quad = lane >> 4;

  bf16x8 qa[2][2];
#pragma unroll
  for (int qt = 0; qt < 2; ++qt) {
    const short* qb_ = Qg + ((size_t)(b * NPOS + n0 + w * 32 + qt * 16 + L)) * 64;
    qa[qt][0] = *(const bf16x8*)(qb_ + quad * 8);
    qa[qt][1] = *(const bf16x8*)(qb_ + 32 + quad * 8);
  }

  f32x4 o[2][4];
#pragma unroll
  for (int qt = 0; qt < 2; ++qt)
#pragma unroll
    for (int nb = 0; nb < 4; ++nb) o[qt][nb] = (f32x4){0.f, 0.f, 0.f, 0.f};
  float rl[2] = {0.f, 0.f};

  int c8 = tid & 7, dr = tid >> 3;
  i32x4 kr0, kr1, vr0, vr1;
  // load tile 0 and stage into buffer 0
  {
    int kt = ks * TILES_PER_SPLIT;
    const i32x4* src = (const i32x4*)(Kg + ((size_t)(b * NPOS + kt * 64)) * 64);
    kr0 = src[tid]; kr1 = src[tid + 256];
    const short* vbase = Vgt + (size_t)b * NPOS + kt * 64 + c8 * 8;
    vr0 = *(const i32x4*)(vbase + (size_t)dr * NTOT);
    vr1 = *(const i32x4*)(vbase + (size_t)(dr + 32) * NTOT);
    i32x4* dst = (i32x4*)Kt[0];
    dst[(tid >> 3) * 10 + (tid & 7)] = kr0;
    dst[((tid + 256) >> 3) * 10 + (tid & 7)] = kr1;
    i32x4* vdst = (i32x4*)Vt[0];
    vdst[dr * 9 + c8] = vr0;
    vdst[(dr + 32) * 9 + c8] = vr1;
  }

  for (int t = 0; t < TILES_PER_SPLIT; ++t) {
    int cur = t & 1;
    // issue next-tile global loads (in flight across the barrier + compute)
    if (t + 1 < TILES_PER_SPLIT) {
      int kt = ks * TILES_PER_SPLIT + t + 1;
      const i32x4* src = (const i32x4*)(Kg + ((size_t)(b * NPOS + kt * 64)) * 64);
      kr0 = src[tid]; kr1 = src[tid + 256];
      const short* vbase = Vgt + (size_t)b * NPOS + kt * 64 + c8 * 8;
      vr0 = *(const i32x4*)(vbase + (size_t)dr * NTOT);
      vr1 = *(const i32x4*)(vbase + (size_t)(dr + 32) * NTOT);
    }
    __syncthreads();   // buf[cur] fully staged (by prev iteration / preamble)

    const i32x4* kt4 = (const i32x4*)Kt[cur];
    const short* vt = Vt[cur];
#pragma unroll
    for (int kti = 0; kti < 4; ++kti) {
      bf16x8 kf0 = __builtin_bit_cast(bf16x8, kt4[(kti * 16 + L) * 10 + quad]);
      bf16x8 kf1 = __builtin_bit_cast(bf16x8, kt4[(kti * 16 + L) * 10 + 4 + quad]);
      bf16x4 pp[2];
#pragma unroll
      for (int qt = 0; qt < 2; ++qt) {
        f32x4 st = {0.f, 0.f, 0.f, 0.f};
        st = __builtin_amdgcn_mfma_f32_16x16x32_bf16(kf0, qa[qt][0], st, 0, 0, 0);
        st = __builtin_amdgcn_mfma_f32_16x16x32_bf16(kf1, qa[qt][1], st, 0, 0, 0);
        float p0 = __builtin_amdgcn_exp2f(st[0]);
        float p1 = __builtin_amdgcn_exp2f(st[1]);
        float p2 = __builtin_amdgcn_exp2f(st[2]);
        float p3 = __builtin_amdgcn_exp2f(st[3]);
        rl[qt] += (p0 + p1) + (p2 + p3);
        u32 lo = __builtin_amdgcn_perm(__builtin_bit_cast(u32, p1), __builtin_bit_cast(u32, p0), 0x07060302u);
        u32 hi = __builtin_amdgcn_perm(__builtin_bit_cast(u32, p3), __builtin_bit_cast(u32, p2), 0x07060302u);
        u32 pr[2] = {lo, hi};
        pp[qt] = __builtin_bit_cast(bf16x4, pr);
      }
#pragma unroll
      for (int nb = 0; nb < 4; ++nb) {
        bf16x4 va = *(const bf16x4*)(vt + (nb * 16 + L) * LDP + kti * 16 + quad * 4);
#pragma unroll
        for (int qt = 0; qt < 2; ++qt)
          o[qt][nb] = __builtin_amdgcn_mfma_f32_16x16x16bf16_1k(va, pp[qt], o[qt][nb], 0, 0, 0);
      }
    }

    // stage next tile into the OTHER buffer (no barrier needed: disjoint buffer;
    // next iteration's barrier orders these writes before their readers)
    if (t + 1 < TILES_PER_SPLIT) {
      int nxt = 1 - cur;
      i32x4* dst = (i32x4*)Kt[nxt];
      dst[(tid >> 3) * 10 + (tid & 7)] = kr0;
      dst[((tid + 256) >> 3) * 10 + (tid & 7)] = kr1;
      i32x4* vdst = (i32x4*)Vt[nxt];
      vdst[dr * 9 + c8] = vr0;
      vdst[(dr + 32) * 9 + c8] = vr1;
    }
  }

#pragma unroll
  for (int qt = 0; qt < 2; ++qt) {
    rl[qt] += __shfl_xor(rl[qt], 16);
    rl[qt] += __shfl_xor(rl[qt], 32);
  }

#pragma unroll
  for (int qt = 0; qt < 2; ++qt) {
    int qg = b * NPOS + n0 + w * 32 + qt * 16 + L;
#pragma unroll
    for (int nb = 0; nb < 4; ++nb)
#pragma unroll
      for (int ip = 0; ip < 2; ++ip) {
        u32 pk = ((u32)(unsigned short)f2bf(o[qt][nb][2 * ip + 1]) << 16) |
                 (u32)(unsigned short)f2bf(o[qt][nb][2 * ip]);
        int d32 = nb * 8 + quad * 2 + ip;
        PoT[((size_t)(ks * 32 + d32)) * NTOT + qg] = pk;
      }
    if (quad == 0) Pl[(size_t)ks * NTOT + qg] = rl[qt];
  }
}

// ---------------- Kernel C: merge + residual + LN2 + MFMA proj_in (+X2) ----------------
// grid (288) x 256 (exact R13).
__global__ __launch_bounds__(256) void k_res_ln2_proj(
    const float* __restrict__ x, const u32* __restrict__ PoT, const float* __restrict__ Pl,
    const float* __restrict__ ln2w, const float* __restrict__ ln2b,
    const float* __restrict__ piw,
    float* __restrict__ X2, float* __restrict__ Hbuf) {
  __shared__ float s1a[4 * 64], s2a[4 * 64];
  __shared__ __align__(16) short xn[64 * 72];
  int t = threadIdx.x;
  int w = t >> 6;
  int p = t & 63;
  int q0 = blockIdx.x * 64;
  int q = q0 + p;
  int b = q / NPOS;
  int nn = q0 % NPOS;
  int n = q % NPOS;

  float lsum = 0.f;
#pragma unroll
  for (int s = 0; s < NSPLIT; ++s) lsum += Pl[(size_t)s * NTOT + q];
  float inv = 1.f / lsum;

  const float* xb = x + (size_t)b * CH * NPOS + n;
  float xr[16];
  float s1 = 0.f, s2 = 0.f;
#pragma unroll
  for (int j2 = 0; j2 < 8; ++j2) {
    float a0 = 0.f, a1 = 0.f;
#pragma unroll
    for (int s = 0; s < NSPLIT; ++s) {
      u32 v = PoT[((size_t)(s * 32 + w * 8 + j2)) * NTOT + q];
      a0 += __builtin_bit_cast(float, v << 16);
      a1 += __builtin_bit_cast(float, v & 0xffff0000u);
    }
    int cl = 2 * j2;
    int c = w * 16 + cl;
    float v0 = xb[(size_t)c * NPOS] + a0 * inv;
    float v1 = xb[(size_t)(c + 1) * NPOS] + a1 * inv;
    xr[cl] = v0; xr[cl + 1] = v1;
    s1 += v0 + v1;
    s2 += v0 * v0 + v1 * v1;
  }
  s1a[w * 64 + p] = s1;
  s2a[w * 64 + p] = s2;
  {
    float* xo = X2 + (size_t)b * CH * NPOS + n;
#pragma unroll
    for (int cl = 0; cl < 16; ++cl) xo[(size_t)(w * 16 + cl) * NPOS] = xr[cl];
  }
  __syncthreads();
  float mu = 0.f, m2 = 0.f;
#pragma unroll
  for (int ww = 0; ww < 4; ++ww) { mu += s1a[ww * 64 + p]; m2 += s2a[ww * 64 + p]; }
  mu *= (1.f / 64.f);
  float var = m2 * (1.f / 64.f) - mu * mu;
  float rstd = rsqrtf(var + 1e-5f);
  {
    u32* xw = (u32*)xn;
#pragma unroll
    for (int j2 = 0; j2 < 8; ++j2) {
      int cl = 2 * j2, c = w * 16 + cl;
      float y0 = (xr[cl] - mu) * rstd * ln2w[c] + ln2b[c];
      float y1 = (xr[cl + 1] - mu) * rstd * ln2w[c + 1] + ln2b[c + 1];
      u32 pk = ((u32)(unsigned short)f2bf(y1) << 16) | (u32)(unsigned short)f2bf(y0);
      xw[p * 36 + w * 8 + j2] = pk;
    }
  }
  __syncthreads();
  int lane = t & 63;
  int L = lane & 15, quad = lane >> 4;
  bf16x8 a0, a1;
  {
    const float* wr = piw + (w * 16 + L) * 64 + quad * 8;
#pragma unroll
    for (int j = 0; j < 8; ++j) { a0[j] = f2bf(wr[j]); a1[j] = f2bf(wr[32 + j]); }
  }
  float* hb = Hbuf + (size_t)b * CH * NPOS + nn;
#pragma unroll
  for (int pt = 0; pt < 4; ++pt) {
    bf16x8 b0 = *(const bf16x8*)(xn + (pt * 16 + L) * 72 + quad * 8);
    bf16x8 b1 = *(const bf16x8*)(xn + (pt * 16 + L) * 72 + 32 + quad * 8);
    f32x4 acc = {0.f, 0.f, 0.f, 0.f};
    acc = __builtin_amdgcn_mfma_f32_16x16x32_bf16(a0, b0, acc, 0, 0, 0);
    acc = __builtin_amdgcn_mfma_f32_16x16x32_bf16(a1, b1, acc, 0, 0, 0);
#pragma unroll
    for (int i = 0; i < 4; ++i)
      hb[(size_t)(w * 16 + quad * 4 + i) * NPOS + pt * 16 + L] = acc[i];
  }
}

// ---------------- Kernel D: per-patch spectral filter ----------------
// grid (288) x 64.
__global__ __launch_bounds__(64) void k_fft(float* __restrict__ Hbuf, const float* __restrict__ fftw) {
  int idx = blockIdx.x * 64 + threadIdx.x;
  int wb = idx % 12;
  int t = idx / 12;
  int hb = t % 12;
  int t2 = t / 12;
  int c = t2 % 64;
  int b = t2 / 64;
  float* base = Hbuf + (size_t)(b * CH + c) * NPOS + (hb * 8) * 96 + wb * 8;
  const float r = 0.70710678118654752440f;
  const float CO[8] = {1.f, r, 0.f, -r, -1.f, -r, 0.f, r};
  const float SI[8] = {0.f, r, 1.f, r, 0.f, -r, -1.f, -r};
  float Ar[8][5], Ai[8][5];
#pragma unroll
  for (int p = 0; p < 8; ++p) {
    f32x4 ra = *(const f32x4*)(base + p * 96);
    f32x4 rb = *(const f32x4*)(base + p * 96 + 4);
    float row[8] = {ra[0], ra[1], ra[2], ra[3], rb[0], rb[1], rb[2], rb[3]};
#pragma unroll
    for (int v = 0; v < 5; ++v) {
      float sr = 0.f, si = 0.f;
#pragma unroll
      for (int q = 0; q < 8; ++q) {
        int k = (q * v) & 7;
        sr += row[q] * CO[k];
        si -= row[q] * SI[k];
      }
      Ar[p][v] = sr;
      Ai[p][v] = si;
    }
  }
  const float* wp = fftw + c * 40;
#pragma unroll
  for (int v = 0; v < 5; ++v) {
    float Br[8], Bi[8];
#pragma unroll
    for (int u = 0; u < 8; ++u) {
      float cr = 0.f, ci = 0.f;
#pragma unroll
      for (int p = 0; p < 8; ++p) {
        int k = (p * u) & 7;
        float cc = CO[k], ss = SI[k];
        cr += Ar[p][v] * cc + Ai[p][v] * ss;
        ci += Ai[p][v] * cc - Ar[p][v] * ss;
      }
      float wv = wp[u * 5 + v];
      Br[u] = cr * wv;
      Bi[u] = ci * wv;
    }
#pragma unroll
    for (int p = 0; p < 8; ++p) {
      float yr = 0.f, yi = 0.f;
#pragma unroll
      for (int u = 0; u < 8; ++u) {
        int k = (p * u) & 7;
        float cc = CO[k], ss = SI[k];
        yr += Br[u] * cc - Bi[u] * ss;
        yi += Bi[u] * cc + Br[u] * ss;
      }
      Ar[p][v] = yr * 0.125f;
      Ai[p][v] = yi * 0.125f;
    }
  }
#pragma unroll
  for (int p = 0; p < 8; ++p) {
    float outv[8];
#pragma unroll
    for (int q = 0; q < 8; ++q) {
      float acc = Ar[p][0] + ((q & 1) ? -Ar[p][4] : Ar[p][4]);
#pragma unroll
      for (int v = 1; v < 4; ++v) {
        int k = (q * v) & 7;
        acc += 2.f * (Ar[p][v] * CO[k] - Ai[p][v] * SI[k]);
      }
      outv[q] = acc * 0.125f;
    }
    f32x4 wa = {outv[0], outv[1], outv[2], outv[3]};
    f32x4 wb2 = {outv[4], outv[5], outv[6], outv[7]};
    *(f32x4*)(base + p * 96) = wa;
    *(f32x4*)(base + p * 96 + 4) = wb2;
  }
}

// ---------------- Kernel E1: dwconv3x3 + gelu-gate -> G ----------------
// grid (72, 32) x 256.
__global__ __launch_bounds__(256) void k_dw_gate(
    const float* __restrict__ Hbuf, const float* __restrict__ dww,
    float* __restrict__ G) {
  int cc = blockIdx.y;
  int q = blockIdx.x * 256 + threadIdx.x;
  int b = q / NPOS, n = q % NPOS;
  int y = n / 96, xx = n % 96;
  const float* h1 = Hbuf + (size_t)(b * CH + cc) * NPOS;
  const float* h2 = Hbuf + (size_t)(b * CH + cc + 32) * NPOS;
  float wd1[9], wd2[9];
#pragma unroll
  for (int ki = 0; ki < 9; ++ki) { wd1[ki] = dww[cc * 9 + ki]; wd2[ki] = dww[(cc + 32) * 9 + ki]; }
  float d1 = 0.f, d2 = 0.f;
  for (int dy = -1; dy <= 1; ++dy) {
    int yy = y + dy;
    if (yy < 0 || yy >= 96) continue;
    for (int dx = -1; dx <= 1; ++dx) {
      int xv = xx + dx;
      if (xv < 0 || xv >= 96) continue;
      int ki = (dy + 1) * 3 + (dx + 1);
      d1 += h1[yy * 96 + xv] * wd1[ki];
      d2 += h2[yy * 96 + xv] * wd2[ki];
    }
  }
  G[(size_t)cc * NTOT + q] = gelu_exact(d1) * d2;
}

// ---------------- Kernel E2: proj_out + residual ----------------
// grid (72, 8) x 256 (exact R13).
__global__ __launch_bounds__(256) void k_proj_out(
    const float* __restrict__ G, const float* __restrict__ poww,
    const float* __restrict__ X2, float* __restrict__ out) {
  int og = blockIdx.y;
  int q = blockIdx.x * 256 + threadIdx.x;
  int b = q / NPOS, n = q % NPOS;
  float g[32];
#pragma unroll
  for (int cg = 0; cg < 32; ++cg) g[cg] = G[(size_t)cg * NTOT + q];
  const float* xr = X2 + (size_t)b * CH * NPOS + n;
  float* ob = out + (size_t)b * CH * NPOS + n;
#pragma unroll
  for (int j = 0; j < 8; ++j) {
    int oc = og * 8 + j;
    const float* prow = poww + oc * 32;
    float acc = xr[(size_t)oc * NPOS];
#pragma unroll
    for (int cg = 0; cg < 32; ++cg) acc += prow[cg] * g[cg];
    ob[(size_t)oc * NPOS] = acc;
  }
}

extern "C" void kernel_launch(void* const* d_in, const int* in_sizes, int n_in,
                              void* d_out, int out_size, void* d_ws, size_t ws_size,
                              hipStream_t stream) {
  const float* x    = (const float*)d_in[0];
  const float* ln1w = (const float*)d_in[1];
  const float* ln1b = (const float*)d_in[2];
  const float* ln2w = (const float*)d_in[3];
  const float* ln2b = (const float*)d_in[4];
  const float* qw   = (const float*)d_in[5];
  const float* qb   = (const float*)d_in[6];
  const float* kw   = (const float*)d_in[7];
  const float* kb   = (const float*)d_in[8];
  const float* vw   = (const float*)d_in[9];
  const float* vb   = (const float*)d_in[10];
  const float* fftw = (const float*)d_in[11];
  const float* piw  = (const float*)d_in[12];
  const float* dww  = (const float*)d_in[13];
  const float* poww = (const float*)d_in[14];

  short* Qg  = (short*)d_ws;
  short* Kg  = Qg + (size_t)NTOT * 64;
  short* Vgt = Kg + (size_t)NTOT * 64;
  u32*   PoT = (u32*)(Vgt + (size_t)NTOT * 64);
  float* Pl  = (float*)(PoT + (size_t)NSPLIT * 32 * NTOT);
  float* X2  = Pl + (size_t)NSPLIT * NTOT;
  float* Hbuf = X2 + (size_t)NTOT * 64;
  float* G   = Hbuf + (size_t)NTOT * 64;

  k_ln_qkv<<<dim3(72, 3, 2), 256, 0, stream>>>(x, ln1w, ln1b, qw, qb, kw, kb, vw, vb, Qg, Kg, Vgt);
  k_attn<<<dim3(72, 2, NSPLIT), 256, 0, stream>>>(Qg, Kg, Vgt, PoT, Pl);
  k_res_ln2_proj<<<dim3(288), 256, 0, stream>>>(x, PoT, Pl, ln2w, ln2b, piw, X2, Hbuf);
  k_fft<<<dim3(288), 64, 0, stream>>>(Hbuf, fftw);
  k_dw_gate<<<dim3(72, 32), 256, 0, stream>>>(Hbuf, dww, G);
  k_proj_out<<<dim3(72, 8), 256, 0, stream>>>(G, poww, X2, (float*)d_out);
}